// Round 4
// baseline (1293.006 us; speedup 1.0000x reference)
//
#include <hip/hip_runtime.h>
#include <cstdint>
#include <cstddef>

#define NN 20000      // nodes
#define NE 640000     // edges
#define DD 128        // feature dim
#define NP 10000      // products (output cols)
#define KO 256        // 2*DD
#define NRT 1250      // NN/16 row-tiles
#define NRT_PAD 1256  // padded to 157*8
#define NCT_PAD 632   // padded col-tiles: 79*8
#define NWG_BIG 12403 // 157*79
#define Q_BIG 1550    // NWG_BIG/8
#define R_BIG 3       // NWG_BIG%8

typedef __attribute__((ext_vector_type(8))) short short8;
typedef __attribute__((ext_vector_type(4))) float f32x4;

static __device__ __forceinline__ unsigned short f2bf(float f){
  uint32_t u = __float_as_uint(f);
  return (unsigned short)((u + 0x7fffu + ((u >> 16) & 1u)) >> 16);
}
static __device__ __forceinline__ float bf2f(unsigned short u){
  return __uint_as_float(((uint32_t)u) << 16);
}

static __device__ __forceinline__ void gload_lds16(const void* g, void* l){
  __builtin_amdgcn_global_load_lds(
      (const __attribute__((address_space(1))) void*)g,
      (__attribute__((address_space(3))) void*)l, 16, 0, 0);
}

// ---------------- CSR build ----------------
__global__ void k_count(const int* __restrict__ dst, int* __restrict__ cnt, int n){
  int i = blockIdx.x * blockDim.x + threadIdx.x;
  if (i < n) atomicAdd(&cnt[dst[i]], 1);
}

__global__ void k_dinv(const int* __restrict__ cnt, float* __restrict__ dinv, int n){
  int i = blockIdx.x * blockDim.x + threadIdx.x;
  if (i < n) dinv[i] = rsqrtf((float)(cnt[i] + 1));  // +1 self-loop
}

__global__ void k_scan(const int* __restrict__ cnt, int* __restrict__ row_off,
                       int* __restrict__ cursor, int n){
  __shared__ int part[1024];
  int t = threadIdx.x;
  int per = (n + 1023) >> 10;
  int base = t * per;
  int s = 0;
  for (int i = 0; i < per; i++){ int idx = base + i; if (idx < n) s += cnt[idx]; }
  part[t] = s;
  __syncthreads();
  for (int off = 1; off < 1024; off <<= 1){
    int v = (t >= off) ? part[t - off] : 0;
    __syncthreads();
    part[t] += v;
    __syncthreads();
  }
  int run = (t == 0) ? 0 : part[t - 1];
  for (int i = 0; i < per; i++){
    int idx = base + i;
    if (idx < n){ row_off[idx] = run; cursor[idx] = run; run += cnt[idx]; }
  }
  if (t == 0) row_off[n] = part[1023];
}

__global__ void k_fill(const int* __restrict__ src, const int* __restrict__ dst,
                       int* __restrict__ cursor, int* __restrict__ col, int n){
  int i = blockIdx.x * blockDim.x + threadIdx.x;
  if (i < n){
    int p = atomicAdd(&cursor[dst[i]], 1);
    col[p] = src[i];
  }
}

// ---------------- packers (MFMA fragment order) ----------------
// frag layout: chunk[(rowtile*KT + ktile)*64 + k8*16 + fr][e]
//   holds X[rowtile*16 + fr][ktile*32 + k8*8 + e], chunk = 8 bf16 = 16B

__global__ void k_gather_frag(const float* __restrict__ tab, const int* __restrict__ ids,
                              unsigned short* __restrict__ xf){
  int node = blockIdx.x * blockDim.y + threadIdx.y;
  int tx = threadIdx.x;            // covers d = tx*4 .. tx*4+3
  if (node >= NN) return;
  const float4 v = *reinterpret_cast<const float4*>(tab + (size_t)ids[node] * DD + tx * 4);
  ushort4 o; o.x = f2bf(v.x); o.y = f2bf(v.y); o.z = f2bf(v.z); o.w = f2bf(v.w);
  size_t chunk = ((size_t)(node >> 4) * 4 + (tx >> 3)) * 64 + ((tx >> 1) & 3) * 16 + (node & 15);
  *reinterpret_cast<ushort4*>(xf + chunk * 8 + (tx & 1) * 4) = o;
}

// small weights W [K][ncols] f32 -> B-fragment order bf16 (tiny, keep simple)
__global__ void k_wfrag(const float* __restrict__ W, unsigned short* __restrict__ Wf,
                        int ncols, int lg2kt, int total){
  int i = blockIdx.x * blockDim.x + threadIdx.x;
  if (i >= total) return;
  int e = i & 7, l = (i >> 3) & 63, rem = i >> 9;
  int kt = rem & ((1 << lg2kt) - 1), ct = rem >> lg2kt;
  int col = ct * 16 + (l & 15);
  int k = kt * 32 + (l >> 4) * 8 + e;
  Wf[i] = (col < ncols) ? f2bf(W[(size_t)k * ncols + col]) : (unsigned short)0;
}

// big weight oW [256][NP] f32 -> frag order bf16, via LDS transpose tile.
// grid (316, 8): tile = 32 k x 32 cols (2 ct, 1 kt). block 256.
__global__ __launch_bounds__(256) void k_wfrag2(const float* __restrict__ W,
                                                unsigned short* __restrict__ Wf){
  __shared__ float tile[32][33];
  const int kb = blockIdx.y * 32, cb = blockIdx.x * 32;
  const int tx = threadIdx.x & 31, ty = threadIdx.x >> 5;   // ty 0..7
  const int col = cb + tx;
  #pragma unroll
  for (int j = 0; j < 4; j++){
    int k = ty + j * 8;
    tile[k][tx] = (col < NP) ? W[(size_t)(kb + k) * NP + col] : 0.f;
  }
  __syncthreads();
  // output: thread t -> ct2 = t>>7, rep = t&1, l = (t>>1)&63; writes e = rep*4..rep*4+3
  const int t = threadIdx.x;
  const int ct2 = t >> 7, rep = t & 1, l = (t >> 1) & 63;
  const int c_loc = ct2 * 16 + (l & 15);
  const int k_loc = (l >> 4) * 8 + rep * 4;
  ushort4 o;
  o.x = f2bf(tile[k_loc + 0][c_loc]);
  o.y = f2bf(tile[k_loc + 1][c_loc]);
  o.z = f2bf(tile[k_loc + 2][c_loc]);
  o.w = f2bf(tile[k_loc + 3][c_loc]);
  const int ct = cb / 16 + ct2, kt = kb / 32;
  *reinterpret_cast<ushort4*>(Wf + ((size_t)(ct * 8 + kt) * 64 + l) * 8 + rep * 4) = o;
}

// ---------------- conv GEMM: hs = dinv * (x @ W), A in regs, no LDS ----------------
__global__ __launch_bounds__(256) void k_conv(const unsigned short* __restrict__ Af,
        const unsigned short* __restrict__ Wf, const float* __restrict__ dinv,
        float* __restrict__ hs){
  int gw = blockIdx.x * 4 + (threadIdx.x >> 6);
  int lane = threadIdx.x & 63;
  bool valid = gw < NRT;
  int R = valid ? gw : (NRT - 1);
  short8 a[4];
  #pragma unroll
  for (int kt = 0; kt < 4; kt++)
    a[kt] = *reinterpret_cast<const short8*>(Af + ((size_t)(R * 4 + kt) * 64 + lane) * 8);
  int fr = lane & 15, fq = lane >> 4;
  #pragma unroll
  for (int ct = 0; ct < 8; ct++){
    f32x4 acc = {0.f, 0.f, 0.f, 0.f};
    #pragma unroll
    for (int kt = 0; kt < 4; kt++){
      short8 b = *reinterpret_cast<const short8*>(Wf + ((size_t)(ct * 4 + kt) * 64 + lane) * 8);
      acc = __builtin_amdgcn_mfma_f32_16x16x32_bf16(a[kt], b, acc, 0, 0, 0);
    }
    if (valid){
      #pragma unroll
      for (int r = 0; r < 4; r++){
        int grow = R * 16 + fq * 4 + r;
        hs[(size_t)grow * DD + ct * 16 + fr] = dinv[grow] * acc[r];
      }
    }
  }
}

// ---------------- aggregation -> frag bf16 ----------------
__global__ void k_agg_frag(const float* __restrict__ hs, const float* __restrict__ dinv,
                           const int* __restrict__ row_off, const int* __restrict__ col,
                           const float* __restrict__ bias, unsigned short* __restrict__ xf,
                           int KT, int toff){
  int node = blockIdx.x * blockDim.y + threadIdx.y;
  int tx = threadIdx.x;
  if (node >= NN) return;
  const float4* h4 = reinterpret_cast<const float4*>(hs);
  float4 acc = h4[(size_t)node * 32 + tx];   // self term (hs pre-scaled by dinv)
  int s = row_off[node], e = row_off[node + 1];
  int i = s;
  for (; i + 1 < e; i += 2){
    int c0 = col[i], c1 = col[i + 1];
    float4 v0 = h4[(size_t)c0 * 32 + tx];
    float4 v1 = h4[(size_t)c1 * 32 + tx];
    acc.x += v0.x + v1.x; acc.y += v0.y + v1.y;
    acc.z += v0.z + v1.z; acc.w += v0.w + v1.w;
  }
  if (i < e){
    float4 v = h4[(size_t)col[i] * 32 + tx];
    acc.x += v.x; acc.y += v.y; acc.z += v.z; acc.w += v.w;
  }
  float dn = dinv[node];
  const float4 b4 = *reinterpret_cast<const float4*>(bias + tx * 4);
  ushort4 o;
  o.x = f2bf(dn * acc.x + b4.x); o.y = f2bf(dn * acc.y + b4.y);
  o.z = f2bf(dn * acc.z + b4.z); o.w = f2bf(dn * acc.w + b4.w);
  size_t chunk = ((size_t)(node >> 4) * KT + toff + (tx >> 3)) * 64 + ((tx >> 1) & 3) * 16 + (node & 15);
  *reinterpret_cast<ushort4*>(xf + chunk * 8 + (tx & 1) * 4) = o;
}

// ---------------- big GEMM (M=20096pad, N=10112pad, K=256) + exp + rowsum ----------------
// 1D grid NWG_BIG; bijective XCD-chunked remap, col-tile fastest within chunk
// (A row-panel stays L2-hot per XCD). Non-temporal stores for the z/e stream.
template<int STORE_BF16>
__global__ __launch_bounds__(256) void k_big(const unsigned short* __restrict__ Af,
        const unsigned short* __restrict__ Bf, const float* __restrict__ ob,
        float* __restrict__ rowsum, unsigned short* __restrict__ wsb,
        float* __restrict__ out){
  __shared__ unsigned short sA[1024 * 8];   // 16KB: [rt8][kt2][lane64][e8]
  __shared__ unsigned short sB[1024 * 8];
  const int tid = threadIdx.x, lane = tid & 63, wid = tid >> 6;
  const int wm = wid >> 1, wn = wid & 1;
  // bijective XCD swizzle (m204): NWG_BIG = 8*Q_BIG + R_BIG
  const int orig = blockIdx.x;
  const int xcd = orig & 7, pos = orig >> 3;
  const int wgid = (xcd < R_BIG ? xcd * (Q_BIG + 1)
                                : R_BIG * (Q_BIG + 1) + (xcd - R_BIG) * Q_BIG) + pos;
  const int brt = (wgid / 79) * 8;   // base 16-row tile
  const int bct = (wgid % 79) * 8;   // base 16-col tile

  f32x4 acc[4][4] = {};

  for (int s = 0; s < 4; s++){
    #pragma unroll
    for (int i = 0; i < 4; i++){
      int c = i * 256 + tid;
      int rt = c >> 7, kt = (c >> 6) & 1, ln = c & 63;
      gload_lds16(Af + (((size_t)(brt + rt) * 8 + s * 2 + kt) * 64 + ln) * 8,
                  (void*)&sA[(size_t)c * 8]);
      gload_lds16(Bf + (((size_t)(bct + rt) * 8 + s * 2 + kt) * 64 + ln) * 8,
                  (void*)&sB[(size_t)c * 8]);
    }
    __syncthreads();
    #pragma unroll
    for (int kk = 0; kk < 2; kk++){
      short8 av[4], bv[4];
      #pragma unroll
      for (int m = 0; m < 4; m++)
        av[m] = *reinterpret_cast<const short8*>(&sA[(((wm * 4 + m) * 2 + kk) * 64 + lane) * 8]);
      #pragma unroll
      for (int n = 0; n < 4; n++)
        bv[n] = *reinterpret_cast<const short8*>(&sB[(((wn * 4 + n) * 2 + kk) * 64 + lane) * 8]);
      #pragma unroll
      for (int m = 0; m < 4; m++)
        #pragma unroll
        for (int n = 0; n < 4; n++)
          acc[m][n] = __builtin_amdgcn_mfma_f32_16x16x32_bf16(av[m], bv[n], acc[m][n], 0, 0, 0);
    }
    __syncthreads();
  }

  const int fr = lane & 15, fq = lane >> 4;
  const int row0 = brt * 16 + wm * 64, col0 = bct * 16 + wn * 64;
  #pragma unroll
  for (int m = 0; m < 4; m++){
    #pragma unroll
    for (int r = 0; r < 4; r++){
      const int grow = row0 + m * 16 + fq * 4 + r;
      const bool rv = grow < NN;
      float rsum = 0.f;
      #pragma unroll
      for (int n = 0; n < 4; n++){
        const int gcol = col0 + n * 16 + fr;
        const bool cv = gcol < NP;
        const float obv = cv ? ob[gcol] : 0.f;
        const float z = acc[m][n][r] + obv;
        const float e = cv ? __expf(z) : 0.f;
        rsum += e;
        if (rv && cv){
          if (STORE_BF16)
            __builtin_nontemporal_store(f2bf(z), &wsb[(size_t)grow * NP + gcol]);
          else
            __builtin_nontemporal_store(e, &out[(size_t)grow * NP + gcol]);
        }
      }
      rsum += __shfl_xor(rsum, 1, 64);
      rsum += __shfl_xor(rsum, 2, 64);
      rsum += __shfl_xor(rsum, 4, 64);
      rsum += __shfl_xor(rsum, 8, 64);
      if (fr == 0 && rv) atomicAdd(&rowsum[grow], rsum);
    }
  }
}

// path A: out = exp(bf16 logit) / rowsum  (streaming, non-temporal)
__global__ __launch_bounds__(256) void k_rescale(const unsigned short* __restrict__ wsb,
        const float* __restrict__ rowsum, float* __restrict__ out){
  const int row = blockIdx.x;
  const float rinv = 1.f / rowsum[row];
  const short8* src = reinterpret_cast<const short8*>(wsb + (size_t)row * NP);
  float* orow = out + (size_t)row * NP;
  for (int c8 = threadIdx.x; c8 < NP / 8; c8 += 256){
    short8 v = __builtin_nontemporal_load(src + c8);
    f32x4 o0, o1;
    o0[0] = __expf(bf2f((unsigned short)v[0])) * rinv;
    o0[1] = __expf(bf2f((unsigned short)v[1])) * rinv;
    o0[2] = __expf(bf2f((unsigned short)v[2])) * rinv;
    o0[3] = __expf(bf2f((unsigned short)v[3])) * rinv;
    o1[0] = __expf(bf2f((unsigned short)v[4])) * rinv;
    o1[1] = __expf(bf2f((unsigned short)v[5])) * rinv;
    o1[2] = __expf(bf2f((unsigned short)v[6])) * rinv;
    o1[3] = __expf(bf2f((unsigned short)v[7])) * rinv;
    __builtin_nontemporal_store(o0, reinterpret_cast<f32x4*>(orow + c8 * 8));
    __builtin_nontemporal_store(o1, reinterpret_cast<f32x4*>(orow + c8 * 8 + 4));
  }
}

// path B: in-place scale
__global__ void k_scale(float* __restrict__ out, const float* __restrict__ rowsum){
  int row = blockIdx.y;
  int c4 = blockIdx.x * blockDim.x + threadIdx.x;
  if (c4 >= NP / 4) return;
  float r = 1.f / rowsum[row];
  float4* p = reinterpret_cast<float4*>(out + (size_t)row * NP) + c4;
  float4 v = *p;
  v.x *= r; v.y *= r; v.z *= r; v.w *= r;
  *p = v;
}

// ---------------- host ----------------
extern "C" void kernel_launch(void* const* d_in, const int* in_sizes, int n_in,
                              void* d_out, int out_size, void* d_ws, size_t ws_size,
                              hipStream_t stream){
  const int*   user_ids = (const int*)d_in[0];
  const int*   prod_ids = (const int*)d_in[1];
  const int*   ei_u     = (const int*)d_in[2];
  const int*   ei_p     = (const int*)d_in[3];
  const float* utab     = (const float*)d_in[4];
  const float* ptab     = (const float*)d_in[5];
  const float* uW       = (const float*)d_in[6];
  const float* ub       = (const float*)d_in[7];
  const float* pW       = (const float*)d_in[8];
  const float* pb       = (const float*)d_in[9];
  const float* oW       = (const float*)d_in[10];
  const float* ob       = (const float*)d_in[11];
  float* out = (float*)d_out;
  (void)in_sizes; (void)n_in; (void)out_size;

  char* w = (char*)d_ws;
  size_t off = 0;
  auto alloc = [&](size_t bytes)->void*{
    void* p = w + off; off += (bytes + 255) & ~(size_t)255; return p;
  };
  int*   cnt_u  = (int*)alloc(NN * 4);
  int*   cnt_p  = (int*)alloc(NN * 4);
  float* dinv_u = (float*)alloc(NN * 4);
  float* dinv_p = (float*)alloc(NN * 4);
  int*   ro_u   = (int*)alloc((NN + 1) * 4);
  int*   ro_p   = (int*)alloc((NN + 1) * 4);
  int*   cur_u  = (int*)alloc(NN * 4);
  int*   cur_p  = (int*)alloc(NN * 4);
  int*   col_u  = (int*)alloc((size_t)NE * 4);
  int*   col_p  = (int*)alloc((size_t)NE * 4);
  unsigned short* xu_f  = (unsigned short*)alloc((size_t)NN * DD * 2);
  unsigned short* xp_f  = (unsigned short*)alloc((size_t)NN * DD * 2);
  unsigned short* xu2_f = (unsigned short*)alloc((size_t)NN * DD * 2);
  unsigned short* xp2_f = (unsigned short*)alloc((size_t)NN * DD * 2);
  unsigned short* comb_f= (unsigned short*)alloc((size_t)NRT_PAD * 8 * 64 * 8 * 2);
  float* hs   = (float*)alloc((size_t)NN * DD * 4);
  unsigned short* WuF0 = (unsigned short*)alloc((size_t)DD * DD * 2);
  unsigned short* WuF1 = (unsigned short*)alloc((size_t)DD * DD * 2);
  unsigned short* WpF0 = (unsigned short*)alloc((size_t)DD * DD * 2);
  unsigned short* WpF1 = (unsigned short*)alloc((size_t)DD * DD * 2);
  unsigned short* WoF  = (unsigned short*)alloc((size_t)NCT_PAD * 8 * 64 * 8 * 2);
  float* rowsum = (float*)alloc(NN * 4);

  const size_t need_ws = (size_t)NN * NP * 2;  // 400 MB bf16 logits
  unsigned short* wsb = nullptr;
  bool pathA = (ws_size > off) && (ws_size - off >= need_ws);
  if (pathA) wsb = (unsigned short*)alloc(need_ws);

  hipMemsetAsync(cnt_u, 0, NN * 4, stream);
  hipMemsetAsync(cnt_p, 0, NN * 4, stream);
  hipMemsetAsync(rowsum, 0, NN * 4, stream);
  hipMemsetAsync(comb_f, 0, (size_t)NRT_PAD * 8 * 64 * 8 * 2, stream);  // zero pad rowtiles

  const int* src_u = ei_u;  const int* dst_u = ei_u + NE;
  const int* src_p = ei_p;  const int* dst_p = ei_p + NE;

  k_count<<<(NE + 255) / 256, 256, 0, stream>>>(dst_u, cnt_u, NE);
  k_count<<<(NE + 255) / 256, 256, 0, stream>>>(dst_p, cnt_p, NE);
  k_dinv<<<(NN + 255) / 256, 256, 0, stream>>>(cnt_u, dinv_u, NN);
  k_dinv<<<(NN + 255) / 256, 256, 0, stream>>>(cnt_p, dinv_p, NN);
  k_scan<<<1, 1024, 0, stream>>>(cnt_u, ro_u, cur_u, NN);
  k_scan<<<1, 1024, 0, stream>>>(cnt_p, ro_p, cur_p, NN);
  k_fill<<<(NE + 255) / 256, 256, 0, stream>>>(src_u, dst_u, cur_u, col_u, NE);
  k_fill<<<(NE + 255) / 256, 256, 0, stream>>>(src_p, dst_p, cur_p, col_p, NE);

  dim3 gblk(32, 8);
  k_gather_frag<<<NN / 8, gblk, 0, stream>>>(utab, user_ids, xu_f);
  k_gather_frag<<<NN / 8, gblk, 0, stream>>>(ptab, prod_ids, xp_f);

  const int wtotS = DD * DD;
  k_wfrag<<<(wtotS + 255) / 256, 256, 0, stream>>>(uW,                    WuF0, DD, 2, wtotS);
  k_wfrag<<<(wtotS + 255) / 256, 256, 0, stream>>>(uW + (size_t)DD * DD,  WuF1, DD, 2, wtotS);
  k_wfrag<<<(wtotS + 255) / 256, 256, 0, stream>>>(pW,                    WpF0, DD, 2, wtotS);
  k_wfrag<<<(wtotS + 255) / 256, 256, 0, stream>>>(pW + (size_t)DD * DD,  WpF1, DD, 2, wtotS);
  // big weight: coalesced LDS-transpose packer
  k_wfrag2<<<dim3(316, 8), 256, 0, stream>>>(oW, WoF);

  const int convGrid = (NRT + 3) / 4;   // 313

  // layer 1
  k_conv<<<convGrid, 256, 0, stream>>>(xu_f, WuF0, dinv_u, hs);
  k_agg_frag<<<NN / 8, gblk, 0, stream>>>(hs, dinv_u, ro_u, col_u, ub, xu2_f, 4, 0);
  k_conv<<<convGrid, 256, 0, stream>>>(xp_f, WpF0, dinv_p, hs);
  k_agg_frag<<<NN / 8, gblk, 0, stream>>>(hs, dinv_p, ro_p, col_p, pb, xp2_f, 4, 0);

  // layer 2 -> comb fragments (user ktiles 0..3, product ktiles 4..7)
  k_conv<<<convGrid, 256, 0, stream>>>(xu2_f, WuF1, dinv_u, hs);
  k_agg_frag<<<NN / 8, gblk, 0, stream>>>(hs, dinv_u, ro_u, col_u, ub + DD, comb_f, 8, 0);
  k_conv<<<convGrid, 256, 0, stream>>>(xp2_f, WpF1, dinv_p, hs);
  k_agg_frag<<<NN / 8, gblk, 0, stream>>>(hs, dinv_p, ro_p, col_p, pb + DD, comb_f, 8, 4);

  // big GEMM + exp + rowsum, then normalize
  if (pathA){
    k_big<1><<<NWG_BIG, 256, 0, stream>>>(comb_f, WoF, ob, rowsum, wsb, out);
    k_rescale<<<NN, 256, 0, stream>>>(wsb, rowsum, out);
  } else {
    k_big<0><<<NWG_BIG, 256, 0, stream>>>(comb_f, WoF, ob, rowsum, nullptr, out);
    k_scale<<<dim3((NP / 4 + 255) / 256, NN), 256, 0, stream>>>(out, rowsum);
  }
}

// Round 5
// 1176.076 us; speedup vs baseline: 1.0994x; 1.0994x over previous
//
#include <hip/hip_runtime.h>
#include <cstdint>
#include <cstddef>

#define NN 20000      // nodes
#define NE 640000     // edges
#define DD 128        // feature dim
#define NP 10000      // products (output cols)
#define KO 256        // 2*DD
#define NRT 1250      // NN/16 row-tiles
#define NRT_PAD 1256  // padded to 157*8
#define NCT_PAD 632   // padded col-tiles: 79*8
#define NWG_BIG 12403 // 157*79
#define Q_BIG 1550    // NWG_BIG/8
#define R_BIG 3       // NWG_BIG%8

typedef __attribute__((ext_vector_type(8))) short short8;
typedef __attribute__((ext_vector_type(4))) float f32x4;

static __device__ __forceinline__ unsigned short f2bf(float f){
  uint32_t u = __float_as_uint(f);
  return (unsigned short)((u + 0x7fffu + ((u >> 16) & 1u)) >> 16);
}
static __device__ __forceinline__ float bf2f(unsigned short u){
  return __uint_as_float(((uint32_t)u) << 16);
}

static __device__ __forceinline__ void gload_lds16(const void* g, void* l){
  __builtin_amdgcn_global_load_lds(
      (const __attribute__((address_space(1))) void*)g,
      (__attribute__((address_space(3))) void*)l, 16, 0, 0);
}

// ---------------- CSR build ----------------
__global__ void k_count(const int* __restrict__ dst, int* __restrict__ cnt, int n){
  int i = blockIdx.x * blockDim.x + threadIdx.x;
  if (i < n) atomicAdd(&cnt[dst[i]], 1);
}

__global__ void k_dinv(const int* __restrict__ cnt, float* __restrict__ dinv, int n){
  int i = blockIdx.x * blockDim.x + threadIdx.x;
  if (i < n) dinv[i] = rsqrtf((float)(cnt[i] + 1));  // +1 self-loop
}

__global__ void k_scan(const int* __restrict__ cnt, int* __restrict__ row_off,
                       int* __restrict__ cursor, int n){
  __shared__ int part[1024];
  int t = threadIdx.x;
  int per = (n + 1023) >> 10;
  int base = t * per;
  int s = 0;
  for (int i = 0; i < per; i++){ int idx = base + i; if (idx < n) s += cnt[idx]; }
  part[t] = s;
  __syncthreads();
  for (int off = 1; off < 1024; off <<= 1){
    int v = (t >= off) ? part[t - off] : 0;
    __syncthreads();
    part[t] += v;
    __syncthreads();
  }
  int run = (t == 0) ? 0 : part[t - 1];
  for (int i = 0; i < per; i++){
    int idx = base + i;
    if (idx < n){ row_off[idx] = run; cursor[idx] = run; run += cnt[idx]; }
  }
  if (t == 0) row_off[n] = part[1023];
}

__global__ void k_fill(const int* __restrict__ src, const int* __restrict__ dst,
                       int* __restrict__ cursor, int* __restrict__ col, int n){
  int i = blockIdx.x * blockDim.x + threadIdx.x;
  if (i < n){
    int p = atomicAdd(&cursor[dst[i]], 1);
    col[p] = src[i];
  }
}

// ---------------- packers (MFMA fragment order) ----------------
// frag layout: chunk[(rowtile*KT + ktile)*64 + k8*16 + fr][e]
//   holds X[rowtile*16 + fr][ktile*32 + k8*8 + e], chunk = 8 bf16 = 16B

__global__ void k_gather_frag(const float* __restrict__ tab, const int* __restrict__ ids,
                              unsigned short* __restrict__ xf){
  int node = blockIdx.x * blockDim.y + threadIdx.y;
  int tx = threadIdx.x;            // covers d = tx*4 .. tx*4+3
  if (node >= NN) return;
  const float4 v = *reinterpret_cast<const float4*>(tab + (size_t)ids[node] * DD + tx * 4);
  ushort4 o; o.x = f2bf(v.x); o.y = f2bf(v.y); o.z = f2bf(v.z); o.w = f2bf(v.w);
  size_t chunk = ((size_t)(node >> 4) * 4 + (tx >> 3)) * 64 + ((tx >> 1) & 3) * 16 + (node & 15);
  *reinterpret_cast<ushort4*>(xf + chunk * 8 + (tx & 1) * 4) = o;
}

// small weights W [K][ncols] f32 -> B-fragment order bf16 (tiny, keep simple)
__global__ void k_wfrag(const float* __restrict__ W, unsigned short* __restrict__ Wf,
                        int ncols, int lg2kt, int total){
  int i = blockIdx.x * blockDim.x + threadIdx.x;
  if (i >= total) return;
  int e = i & 7, l = (i >> 3) & 63, rem = i >> 9;
  int kt = rem & ((1 << lg2kt) - 1), ct = rem >> lg2kt;
  int col = ct * 16 + (l & 15);
  int k = kt * 32 + (l >> 4) * 8 + e;
  Wf[i] = (col < ncols) ? f2bf(W[(size_t)k * ncols + col]) : (unsigned short)0;
}

// big weight oW [256][NP] f32 -> frag order bf16, via LDS transpose tile.
__global__ __launch_bounds__(256) void k_wfrag2(const float* __restrict__ W,
                                                unsigned short* __restrict__ Wf){
  __shared__ float tile[32][33];
  const int kb = blockIdx.y * 32, cb = blockIdx.x * 32;
  const int tx = threadIdx.x & 31, ty = threadIdx.x >> 5;   // ty 0..7
  const int col = cb + tx;
  #pragma unroll
  for (int j = 0; j < 4; j++){
    int k = ty + j * 8;
    tile[k][tx] = (col < NP) ? W[(size_t)(kb + k) * NP + col] : 0.f;
  }
  __syncthreads();
  const int t = threadIdx.x;
  const int ct2 = t >> 7, rep = t & 1, l = (t >> 1) & 63;
  const int c_loc = ct2 * 16 + (l & 15);
  const int k_loc = (l >> 4) * 8 + rep * 4;
  ushort4 o;
  o.x = f2bf(tile[k_loc + 0][c_loc]);
  o.y = f2bf(tile[k_loc + 1][c_loc]);
  o.z = f2bf(tile[k_loc + 2][c_loc]);
  o.w = f2bf(tile[k_loc + 3][c_loc]);
  const int ct = cb / 16 + ct2, kt = kb / 32;
  *reinterpret_cast<ushort4*>(Wf + ((size_t)(ct * 8 + kt) * 64 + l) * 8 + rep * 4) = o;
}

// ---------------- conv GEMM: hsb = bf16(dinv * (x @ W)), A in regs, no LDS ----------------
__global__ __launch_bounds__(256) void k_conv(const unsigned short* __restrict__ Af,
        const unsigned short* __restrict__ Wf, const float* __restrict__ dinv,
        unsigned short* __restrict__ hsb){
  int gw = blockIdx.x * 4 + (threadIdx.x >> 6);
  int lane = threadIdx.x & 63;
  bool valid = gw < NRT;
  int R = valid ? gw : (NRT - 1);
  short8 a[4];
  #pragma unroll
  for (int kt = 0; kt < 4; kt++)
    a[kt] = *reinterpret_cast<const short8*>(Af + ((size_t)(R * 4 + kt) * 64 + lane) * 8);
  int fr = lane & 15, fq = lane >> 4;
  #pragma unroll
  for (int ct = 0; ct < 8; ct++){
    f32x4 acc = {0.f, 0.f, 0.f, 0.f};
    #pragma unroll
    for (int kt = 0; kt < 4; kt++){
      short8 b = *reinterpret_cast<const short8*>(Wf + ((size_t)(ct * 4 + kt) * 64 + lane) * 8);
      acc = __builtin_amdgcn_mfma_f32_16x16x32_bf16(a[kt], b, acc, 0, 0, 0);
    }
    if (valid){
      #pragma unroll
      for (int r = 0; r < 4; r++){
        int grow = R * 16 + fq * 4 + r;
        hsb[(size_t)grow * DD + ct * 16 + fr] = f2bf(dinv[grow] * acc[r]);
      }
    }
  }
}

// ---------------- aggregation (bf16 hs) -> frag bf16 ----------------
// block (16,16): 16 lanes per node, each lane owns 8 dims = 1 frag chunk.
__global__ void k_agg_frag(const unsigned short* __restrict__ hsb, const float* __restrict__ dinv,
                           const int* __restrict__ row_off, const int* __restrict__ col,
                           const float* __restrict__ bias, unsigned short* __restrict__ xf,
                           int KT, int toff){
  int node = blockIdx.x * blockDim.y + threadIdx.y;
  int tx = threadIdx.x;   // 0..15; dims tx*8..tx*8+7
  if (node >= NN) return;
  const short8* h8 = reinterpret_cast<const short8*>(hsb);
  float a[8];
  {
    short8 v = h8[(size_t)node * 16 + tx];
    #pragma unroll
    for (int j = 0; j < 8; j++) a[j] = bf2f((unsigned short)v[j]);
  }
  int s = row_off[node], e = row_off[node + 1];
  for (int i = s; i < e; i++){
    short8 v = h8[(size_t)col[i] * 16 + tx];
    #pragma unroll
    for (int j = 0; j < 8; j++) a[j] += bf2f((unsigned short)v[j]);
  }
  float dn = dinv[node];
  short8 ov;
  #pragma unroll
  for (int j = 0; j < 8; j++)
    ov[j] = (short)f2bf(dn * a[j] + bias[tx * 8 + j]);
  // d = tx*8+j: ktile = tx>>2, k8 = tx&3, e = j -> exactly one chunk per lane
  size_t chunk = ((size_t)(node >> 4) * KT + toff + (tx >> 2)) * 64 + (tx & 3) * 16 + (node & 15);
  *reinterpret_cast<short8*>(xf + chunk * 8) = ov;
}

// ---------------- big GEMM (M=20096pad, N=10112pad, K=256) + exp + rowsum ----------------
// XCD-chunked bijective remap; LDS-staged full-line epilogue (pathA).
template<int STORE_BF16>
__global__ __launch_bounds__(256) void k_big(const unsigned short* __restrict__ Af,
        const unsigned short* __restrict__ Bf, const float* __restrict__ ob,
        float* __restrict__ rowsum, unsigned short* __restrict__ wsb,
        float* __restrict__ out){
  __shared__ unsigned short smem[16384];   // 32KB: sA(16KB)+sB(16KB), reused as 128x128 bf16 tile
  unsigned short* sA = smem;
  unsigned short* sB = smem + 8192;
  const int tid = threadIdx.x, lane = tid & 63, wid = tid >> 6;
  const int wm = wid >> 1, wn = wid & 1;
  // bijective XCD swizzle (m204): NWG_BIG = 8*Q_BIG + R_BIG
  const int orig = blockIdx.x;
  const int xcd = orig & 7, pos = orig >> 3;
  const int wgid = (xcd < R_BIG ? xcd * (Q_BIG + 1)
                                : R_BIG * (Q_BIG + 1) + (xcd - R_BIG) * Q_BIG) + pos;
  const int brt = (wgid / 79) * 8;   // base 16-row tile
  const int bct = (wgid % 79) * 8;   // base 16-col tile

  f32x4 acc[4][4] = {};

  for (int s = 0; s < 4; s++){
    #pragma unroll
    for (int i = 0; i < 4; i++){
      int c = i * 256 + tid;
      int rt = c >> 7, kt = (c >> 6) & 1, ln = c & 63;
      gload_lds16(Af + (((size_t)(brt + rt) * 8 + s * 2 + kt) * 64 + ln) * 8,
                  (void*)&sA[(size_t)c * 8]);
      gload_lds16(Bf + (((size_t)(bct + rt) * 8 + s * 2 + kt) * 64 + ln) * 8,
                  (void*)&sB[(size_t)c * 8]);
    }
    __syncthreads();
    #pragma unroll
    for (int kk = 0; kk < 2; kk++){
      short8 av[4], bv[4];
      #pragma unroll
      for (int m = 0; m < 4; m++)
        av[m] = *reinterpret_cast<const short8*>(&sA[(((wm * 4 + m) * 2 + kk) * 64 + lane) * 8]);
      #pragma unroll
      for (int n = 0; n < 4; n++)
        bv[n] = *reinterpret_cast<const short8*>(&sB[(((wn * 4 + n) * 2 + kk) * 64 + lane) * 8]);
      #pragma unroll
      for (int m = 0; m < 4; m++)
        #pragma unroll
        for (int n = 0; n < 4; n++)
          acc[m][n] = __builtin_amdgcn_mfma_f32_16x16x32_bf16(av[m], bv[n], acc[m][n], 0, 0, 0);
    }
    __syncthreads();
  }

  const int fr = lane & 15, fq = lane >> 4;
  if (STORE_BF16){
    // epilogue: exp+rowsum from regs; bf16 logits -> swizzled LDS tile -> full-line nt stores
    #pragma unroll
    for (int m = 0; m < 4; m++){
      #pragma unroll
      for (int r = 0; r < 4; r++){
        const int row_loc = wm * 64 + m * 16 + fq * 4 + r;
        const int grow = brt * 16 + row_loc;
        float rsum = 0.f;
        #pragma unroll
        for (int n = 0; n < 4; n++){
          const int col_loc = wn * 64 + n * 16 + fr;
          const int gcol = bct * 16 + col_loc;
          const bool cv = gcol < NP;
          const float obv = cv ? ob[gcol] : 0.f;
          const float z = acc[m][n][r] + obv;
          rsum += cv ? __expf(z) : 0.f;
          const int chunk = (col_loc >> 3) ^ (fq << 1);   // bank-spread swizzle
          smem[row_loc * 128 + chunk * 8 + (col_loc & 7)] = f2bf(z);
        }
        rsum += __shfl_xor(rsum, 1, 64);
        rsum += __shfl_xor(rsum, 2, 64);
        rsum += __shfl_xor(rsum, 4, 64);
        rsum += __shfl_xor(rsum, 8, 64);
        if (fr == 0 && grow < NN) atomicAdd(&rowsum[grow], rsum);
      }
    }
    __syncthreads();
    const int trow = tid >> 4, tc = tid & 15;
    #pragma unroll
    for (int p = 0; p < 8; p++){
      const int row_loc = p * 16 + trow;
      const int grow = brt * 16 + row_loc;
      const int chunk = tc ^ (((row_loc >> 2) & 3) << 1);
      short8 v = *reinterpret_cast<const short8*>(&smem[row_loc * 128 + chunk * 8]);
      const int gcol = bct * 16 + tc * 8;
      if (grow < NN && gcol < NP)
        __builtin_nontemporal_store(v,
            reinterpret_cast<short8*>(&wsb[(size_t)grow * NP + gcol]));
    }
  } else {
    // fallback: fp32 exp to out + in-place scale later
    #pragma unroll
    for (int m = 0; m < 4; m++){
      #pragma unroll
      for (int r = 0; r < 4; r++){
        const int grow = brt * 16 + wm * 64 + m * 16 + fq * 4 + r;
        const bool rv = grow < NN;
        float rsum = 0.f;
        #pragma unroll
        for (int n = 0; n < 4; n++){
          const int gcol = bct * 16 + wn * 64 + n * 16 + fr;
          const bool cv = gcol < NP;
          const float obv = cv ? ob[gcol] : 0.f;
          const float e = cv ? __expf(acc[m][n][r] + obv) : 0.f;
          rsum += e;
          if (rv && cv) out[(size_t)grow * NP + gcol] = e;
        }
        rsum += __shfl_xor(rsum, 1, 64);
        rsum += __shfl_xor(rsum, 2, 64);
        rsum += __shfl_xor(rsum, 4, 64);
        rsum += __shfl_xor(rsum, 8, 64);
        if (fr == 0 && rv) atomicAdd(&rowsum[grow], rsum);
      }
    }
  }
}

// path A: out = exp(bf16 logit) / rowsum  (streaming, non-temporal)
__global__ __launch_bounds__(256) void k_rescale(const unsigned short* __restrict__ wsb,
        const float* __restrict__ rowsum, float* __restrict__ out){
  const int row = blockIdx.x;
  const float rinv = 1.f / rowsum[row];
  const short8* src = reinterpret_cast<const short8*>(wsb + (size_t)row * NP);
  float* orow = out + (size_t)row * NP;
  for (int c8 = threadIdx.x; c8 < NP / 8; c8 += 256){
    short8 v = __builtin_nontemporal_load(src + c8);
    f32x4 o0, o1;
    o0[0] = __expf(bf2f((unsigned short)v[0])) * rinv;
    o0[1] = __expf(bf2f((unsigned short)v[1])) * rinv;
    o0[2] = __expf(bf2f((unsigned short)v[2])) * rinv;
    o0[3] = __expf(bf2f((unsigned short)v[3])) * rinv;
    o1[0] = __expf(bf2f((unsigned short)v[4])) * rinv;
    o1[1] = __expf(bf2f((unsigned short)v[5])) * rinv;
    o1[2] = __expf(bf2f((unsigned short)v[6])) * rinv;
    o1[3] = __expf(bf2f((unsigned short)v[7])) * rinv;
    __builtin_nontemporal_store(o0, reinterpret_cast<f32x4*>(orow + c8 * 8));
    __builtin_nontemporal_store(o1, reinterpret_cast<f32x4*>(orow + c8 * 8 + 4));
  }
}

// path B: in-place scale
__global__ void k_scale(float* __restrict__ out, const float* __restrict__ rowsum){
  int row = blockIdx.y;
  int c4 = blockIdx.x * blockDim.x + threadIdx.x;
  if (c4 >= NP / 4) return;
  float r = 1.f / rowsum[row];
  float4* p = reinterpret_cast<float4*>(out + (size_t)row * NP) + c4;
  float4 v = *p;
  v.x *= r; v.y *= r; v.z *= r; v.w *= r;
  *p = v;
}

// ---------------- host ----------------
extern "C" void kernel_launch(void* const* d_in, const int* in_sizes, int n_in,
                              void* d_out, int out_size, void* d_ws, size_t ws_size,
                              hipStream_t stream){
  const int*   user_ids = (const int*)d_in[0];
  const int*   prod_ids = (const int*)d_in[1];
  const int*   ei_u     = (const int*)d_in[2];
  const int*   ei_p     = (const int*)d_in[3];
  const float* utab     = (const float*)d_in[4];
  const float* ptab     = (const float*)d_in[5];
  const float* uW       = (const float*)d_in[6];
  const float* ub       = (const float*)d_in[7];
  const float* pW       = (const float*)d_in[8];
  const float* pb       = (const float*)d_in[9];
  const float* oW       = (const float*)d_in[10];
  const float* ob       = (const float*)d_in[11];
  float* out = (float*)d_out;
  (void)in_sizes; (void)n_in; (void)out_size;

  char* w = (char*)d_ws;
  size_t off = 0;
  auto alloc = [&](size_t bytes)->void*{
    void* p = w + off; off += (bytes + 255) & ~(size_t)255; return p;
  };
  int*   cnt_u  = (int*)alloc(NN * 4);
  int*   cnt_p  = (int*)alloc(NN * 4);
  float* dinv_u = (float*)alloc(NN * 4);
  float* dinv_p = (float*)alloc(NN * 4);
  int*   ro_u   = (int*)alloc((NN + 1) * 4);
  int*   ro_p   = (int*)alloc((NN + 1) * 4);
  int*   cur_u  = (int*)alloc(NN * 4);
  int*   cur_p  = (int*)alloc(NN * 4);
  int*   col_u  = (int*)alloc((size_t)NE * 4);
  int*   col_p  = (int*)alloc((size_t)NE * 4);
  unsigned short* xu_f  = (unsigned short*)alloc((size_t)NN * DD * 2);
  unsigned short* xp_f  = (unsigned short*)alloc((size_t)NN * DD * 2);
  unsigned short* xu2_f = (unsigned short*)alloc((size_t)NN * DD * 2);
  unsigned short* xp2_f = (unsigned short*)alloc((size_t)NN * DD * 2);
  unsigned short* comb_f= (unsigned short*)alloc((size_t)NRT_PAD * 8 * 64 * 8 * 2);
  unsigned short* hsb  = (unsigned short*)alloc((size_t)NN * DD * 2);
  unsigned short* WuF0 = (unsigned short*)alloc((size_t)DD * DD * 2);
  unsigned short* WuF1 = (unsigned short*)alloc((size_t)DD * DD * 2);
  unsigned short* WpF0 = (unsigned short*)alloc((size_t)DD * DD * 2);
  unsigned short* WpF1 = (unsigned short*)alloc((size_t)DD * DD * 2);
  unsigned short* WoF  = (unsigned short*)alloc((size_t)NCT_PAD * 8 * 64 * 8 * 2);
  float* rowsum = (float*)alloc(NN * 4);

  const size_t need_ws = (size_t)NN * NP * 2;  // 400 MB bf16 logits
  unsigned short* wsb = nullptr;
  bool pathA = (ws_size > off) && (ws_size - off >= need_ws);
  if (pathA) wsb = (unsigned short*)alloc(need_ws);

  hipMemsetAsync(cnt_u, 0, NN * 4, stream);
  hipMemsetAsync(cnt_p, 0, NN * 4, stream);
  hipMemsetAsync(rowsum, 0, NN * 4, stream);
  hipMemsetAsync(comb_f, 0, (size_t)NRT_PAD * 8 * 64 * 8 * 2, stream);  // zero pad rowtiles

  const int* src_u = ei_u;  const int* dst_u = ei_u + NE;
  const int* src_p = ei_p;  const int* dst_p = ei_p + NE;

  k_count<<<(NE + 255) / 256, 256, 0, stream>>>(dst_u, cnt_u, NE);
  k_count<<<(NE + 255) / 256, 256, 0, stream>>>(dst_p, cnt_p, NE);
  k_dinv<<<(NN + 255) / 256, 256, 0, stream>>>(cnt_u, dinv_u, NN);
  k_dinv<<<(NN + 255) / 256, 256, 0, stream>>>(cnt_p, dinv_p, NN);
  k_scan<<<1, 1024, 0, stream>>>(cnt_u, ro_u, cur_u, NN);
  k_scan<<<1, 1024, 0, stream>>>(cnt_p, ro_p, cur_p, NN);
  k_fill<<<(NE + 255) / 256, 256, 0, stream>>>(src_u, dst_u, cur_u, col_u, NE);
  k_fill<<<(NE + 255) / 256, 256, 0, stream>>>(src_p, dst_p, cur_p, col_p, NE);

  dim3 gblk(32, 8);
  k_gather_frag<<<NN / 8, gblk, 0, stream>>>(utab, user_ids, xu_f);
  k_gather_frag<<<NN / 8, gblk, 0, stream>>>(ptab, prod_ids, xp_f);

  const int wtotS = DD * DD;
  k_wfrag<<<(wtotS + 255) / 256, 256, 0, stream>>>(uW,                    WuF0, DD, 2, wtotS);
  k_wfrag<<<(wtotS + 255) / 256, 256, 0, stream>>>(uW + (size_t)DD * DD,  WuF1, DD, 2, wtotS);
  k_wfrag<<<(wtotS + 255) / 256, 256, 0, stream>>>(pW,                    WpF0, DD, 2, wtotS);
  k_wfrag<<<(wtotS + 255) / 256, 256, 0, stream>>>(pW + (size_t)DD * DD,  WpF1, DD, 2, wtotS);
  k_wfrag2<<<dim3(316, 8), 256, 0, stream>>>(oW, WoF);

  const int convGrid = (NRT + 3) / 4;   // 313
  dim3 aggBlk(16, 16);
  const int aggGrid = (NN + 15) / 16;

  // layer 1
  k_conv<<<convGrid, 256, 0, stream>>>(xu_f, WuF0, dinv_u, hsb);
  k_agg_frag<<<aggGrid, aggBlk, 0, stream>>>(hsb, dinv_u, ro_u, col_u, ub, xu2_f, 4, 0);
  k_conv<<<convGrid, 256, 0, stream>>>(xp_f, WpF0, dinv_p, hsb);
  k_agg_frag<<<aggGrid, aggBlk, 0, stream>>>(hsb, dinv_p, ro_p, col_p, pb, xp2_f, 4, 0);

  // layer 2 -> comb fragments (user ktiles 0..3, product ktiles 4..7)
  k_conv<<<convGrid, 256, 0, stream>>>(xu2_f, WuF1, dinv_u, hsb);
  k_agg_frag<<<aggGrid, aggBlk, 0, stream>>>(hsb, dinv_u, ro_u, col_u, ub + DD, comb_f, 8, 0);
  k_conv<<<convGrid, 256, 0, stream>>>(xp2_f, WpF1, dinv_p, hsb);
  k_agg_frag<<<aggGrid, aggBlk, 0, stream>>>(hsb, dinv_p, ro_p, col_p, pb + DD, comb_f, 8, 4);

  // big GEMM + exp + rowsum, then normalize
  if (pathA){
    k_big<1><<<NWG_BIG, 256, 0, stream>>>(comb_f, WoF, ob, rowsum, wsb, out);
    k_rescale<<<NN, 256, 0, stream>>>(wsb, rowsum, out);
  } else {
    k_big<0><<<NWG_BIG, 256, 0, stream>>>(comb_f, WoF, ob, rowsum, nullptr, out);
    k_scale<<<dim3((NP / 4 + 255) / 256, NN), 256, 0, stream>>>(out, rowsum);
  }
}

// Round 6
// 950.975 us; speedup vs baseline: 1.3597x; 1.2367x over previous
//
#include <hip/hip_runtime.h>
#include <cstdint>
#include <cstddef>

#define NN 20000      // nodes
#define NE 640000     // edges
#define DD 128        // feature dim
#define NP 10000      // products (output cols)
#define KO 256        // 2*DD
#define NRT 1250      // NN/16 row-tiles
#define NRT_PAD 1256  // padded to 157*8 (157 row panels of 128)
#define NCT_PAD 632   // padded col-tiles: 79*8 (79 col panels of 128)
#define NWG_BIG 12800 // 25 super-tiles * 512 (padded; 157*79=12403 real)

typedef __attribute__((ext_vector_type(8))) short short8;
typedef __attribute__((ext_vector_type(4))) float f32x4;

static __device__ __forceinline__ unsigned short f2bf(float f){
  uint32_t u = __float_as_uint(f);
  return (unsigned short)((u + 0x7fffu + ((u >> 16) & 1u)) >> 16);
}
static __device__ __forceinline__ float bf2f(unsigned short u){
  return __uint_as_float(((uint32_t)u) << 16);
}

static __device__ __forceinline__ void gload_lds16(const void* g, void* l){
  __builtin_amdgcn_global_load_lds(
      (const __attribute__((address_space(1))) void*)g,
      (__attribute__((address_space(3))) void*)l, 16, 0, 0);
}

// ---------------- CSR build ----------------
__global__ void k_count(const int* __restrict__ dst, int* __restrict__ cnt, int n){
  int i = blockIdx.x * blockDim.x + threadIdx.x;
  if (i < n) atomicAdd(&cnt[dst[i]], 1);
}

__global__ void k_dinv(const int* __restrict__ cnt, float* __restrict__ dinv, int n){
  int i = blockIdx.x * blockDim.x + threadIdx.x;
  if (i < n) dinv[i] = rsqrtf((float)(cnt[i] + 1));  // +1 self-loop
}

__global__ void k_scan(const int* __restrict__ cnt, int* __restrict__ row_off,
                       int* __restrict__ cursor, int n){
  __shared__ int part[1024];
  int t = threadIdx.x;
  int per = (n + 1023) >> 10;
  int base = t * per;
  int s = 0;
  for (int i = 0; i < per; i++){ int idx = base + i; if (idx < n) s += cnt[idx]; }
  part[t] = s;
  __syncthreads();
  for (int off = 1; off < 1024; off <<= 1){
    int v = (t >= off) ? part[t - off] : 0;
    __syncthreads();
    part[t] += v;
    __syncthreads();
  }
  int run = (t == 0) ? 0 : part[t - 1];
  for (int i = 0; i < per; i++){
    int idx = base + i;
    if (idx < n){ row_off[idx] = run; cursor[idx] = run; run += cnt[idx]; }
  }
  if (t == 0) row_off[n] = part[1023];
}

__global__ void k_fill(const int* __restrict__ src, const int* __restrict__ dst,
                       int* __restrict__ cursor, int* __restrict__ col, int n){
  int i = blockIdx.x * blockDim.x + threadIdx.x;
  if (i < n){
    int p = atomicAdd(&cursor[dst[i]], 1);
    col[p] = src[i];
  }
}

// ---------------- packers (MFMA fragment order) ----------------
// frag layout: chunk[(rowtile*KT + ktile)*64 + k8*16 + fr][e]
//   holds X[rowtile*16 + fr][ktile*32 + k8*8 + e], chunk = 8 bf16 = 16B

__global__ void k_gather_frag(const float* __restrict__ tab, const int* __restrict__ ids,
                              unsigned short* __restrict__ xf){
  int node = blockIdx.x * blockDim.y + threadIdx.y;
  int tx = threadIdx.x;            // covers d = tx*4 .. tx*4+3
  if (node >= NN) return;
  const float4 v = *reinterpret_cast<const float4*>(tab + (size_t)ids[node] * DD + tx * 4);
  ushort4 o; o.x = f2bf(v.x); o.y = f2bf(v.y); o.z = f2bf(v.z); o.w = f2bf(v.w);
  size_t chunk = ((size_t)(node >> 4) * 4 + (tx >> 3)) * 64 + ((tx >> 1) & 3) * 16 + (node & 15);
  *reinterpret_cast<ushort4*>(xf + chunk * 8 + (tx & 1) * 4) = o;
}

// small weights W [K][ncols] f32 -> B-fragment order bf16
__global__ void k_wfrag(const float* __restrict__ W, unsigned short* __restrict__ Wf,
                        int ncols, int lg2kt, int total){
  int i = blockIdx.x * blockDim.x + threadIdx.x;
  if (i >= total) return;
  int e = i & 7, l = (i >> 3) & 63, rem = i >> 9;
  int kt = rem & ((1 << lg2kt) - 1), ct = rem >> lg2kt;
  int col = ct * 16 + (l & 15);
  int k = kt * 32 + (l >> 4) * 8 + e;
  Wf[i] = (col < ncols) ? f2bf(W[(size_t)k * ncols + col]) : (unsigned short)0;
}

// big weight oW [256][NP] f32 -> frag order bf16, via LDS transpose tile.
__global__ __launch_bounds__(256) void k_wfrag2(const float* __restrict__ W,
                                                unsigned short* __restrict__ Wf){
  __shared__ float tile[32][33];
  const int kb = blockIdx.y * 32, cb = blockIdx.x * 32;
  const int tx = threadIdx.x & 31, ty = threadIdx.x >> 5;   // ty 0..7
  const int col = cb + tx;
  #pragma unroll
  for (int j = 0; j < 4; j++){
    int k = ty + j * 8;
    tile[k][tx] = (col < NP) ? W[(size_t)(kb + k) * NP + col] : 0.f;
  }
  __syncthreads();
  const int t = threadIdx.x;
  const int ct2 = t >> 7, rep = t & 1, l = (t >> 1) & 63;
  const int c_loc = ct2 * 16 + (l & 15);
  const int k_loc = (l >> 4) * 8 + rep * 4;
  ushort4 o;
  o.x = f2bf(tile[k_loc + 0][c_loc]);
  o.y = f2bf(tile[k_loc + 1][c_loc]);
  o.z = f2bf(tile[k_loc + 2][c_loc]);
  o.w = f2bf(tile[k_loc + 3][c_loc]);
  const int ct = cb / 16 + ct2, kt = kb / 32;
  *reinterpret_cast<ushort4*>(Wf + ((size_t)(ct * 8 + kt) * 64 + l) * 8 + rep * 4) = o;
}

// ---------------- conv GEMM: hsb = bf16(dinv * (x @ W)), A in regs, no LDS ----------------
__global__ __launch_bounds__(256) void k_conv(const unsigned short* __restrict__ Af,
        const unsigned short* __restrict__ Wf, const float* __restrict__ dinv,
        unsigned short* __restrict__ hsb){
  int gw = blockIdx.x * 4 + (threadIdx.x >> 6);
  int lane = threadIdx.x & 63;
  bool valid = gw < NRT;
  int R = valid ? gw : (NRT - 1);
  short8 a[4];
  #pragma unroll
  for (int kt = 0; kt < 4; kt++)
    a[kt] = *reinterpret_cast<const short8*>(Af + ((size_t)(R * 4 + kt) * 64 + lane) * 8);
  int fr = lane & 15, fq = lane >> 4;
  #pragma unroll
  for (int ct = 0; ct < 8; ct++){
    f32x4 acc = {0.f, 0.f, 0.f, 0.f};
    #pragma unroll
    for (int kt = 0; kt < 4; kt++){
      short8 b = *reinterpret_cast<const short8*>(Wf + ((size_t)(ct * 4 + kt) * 64 + lane) * 8);
      acc = __builtin_amdgcn_mfma_f32_16x16x32_bf16(a[kt], b, acc, 0, 0, 0);
    }
    if (valid){
      #pragma unroll
      for (int r = 0; r < 4; r++){
        int grow = R * 16 + fq * 4 + r;
        hsb[(size_t)grow * DD + ct * 16 + fr] = f2bf(dinv[grow] * acc[r]);
      }
    }
  }
}

// ---------------- aggregation (bf16 hs) -> frag bf16 ----------------
__global__ void k_agg_frag(const unsigned short* __restrict__ hsb, const float* __restrict__ dinv,
                           const int* __restrict__ row_off, const int* __restrict__ col,
                           const float* __restrict__ bias, unsigned short* __restrict__ xf,
                           int KT, int toff){
  int node = blockIdx.x * blockDim.y + threadIdx.y;
  int tx = threadIdx.x;   // 0..15; dims tx*8..tx*8+7
  if (node >= NN) return;
  const short8* h8 = reinterpret_cast<const short8*>(hsb);
  float a[8];
  {
    short8 v = h8[(size_t)node * 16 + tx];
    #pragma unroll
    for (int j = 0; j < 8; j++) a[j] = bf2f((unsigned short)v[j]);
  }
  int s = row_off[node], e = row_off[node + 1];
  for (int i = s; i < e; i++){
    short8 v = h8[(size_t)col[i] * 16 + tx];
    #pragma unroll
    for (int j = 0; j < 8; j++) a[j] += bf2f((unsigned short)v[j]);
  }
  float dn = dinv[node];
  short8 ov;
  #pragma unroll
  for (int j = 0; j < 8; j++)
    ov[j] = (short)f2bf(dn * a[j] + bias[tx * 8 + j]);
  size_t chunk = ((size_t)(node >> 4) * KT + toff + (tx >> 2)) * 64 + (tx & 3) * 16 + (node & 15);
  *reinterpret_cast<short8*>(xf + chunk * 8) = ov;
}

// ---------------- big GEMM, two-pass recompute softmax ----------------
// PASS 0: GEMM + exp + atomic rowsum (no stores).
// PASS 1: GEMM again, out = exp(z)/rowsum, direct full-line fp32 nt stores.
// Super-tile order (32 row panels x 16 col panels = 512 blocks: A 2MB + B 1MB < 4MB L2)
// + bijective XCD chunking (12800 = 8*1600). 2-phase dbuf staging, counted vmcnt.
template<int PASS>
__global__ __launch_bounds__(256) void k_big(const unsigned short* __restrict__ Af,
        const unsigned short* __restrict__ Bf, const float* __restrict__ ob,
        float* __restrict__ rowsum, float* __restrict__ out){
  __shared__ unsigned short smem[2][16384];   // 2 bufs x (A 16KB | B 16KB)
  const int tid = threadIdx.x, lane = tid & 63, wid = tid >> 6;
  const int wm = wid >> 1, wn = wid & 1;

  const int orig = blockIdx.x;
  const int wgid = (orig & 7) * 1600 + (orig >> 3);     // XCD-chunked, bijective (R=0)
  const int st = wgid >> 9, within = wgid & 511;
  const int sr = st / 5, sc = st % 5;
  const int rp = sr * 32 + (within & 31);               // row panel (128 rows)
  const int cp = sc * 16 + (within >> 5);               // col panel (128 cols)
  if (rp >= 157 || cp >= 79) return;
  const int brt = rp * 8, bct = cp * 8;                 // base 16-tiles

#define STAGE(buf, s) do{                                                      \
    _Pragma("unroll")                                                          \
    for (int i_ = 0; i_ < 4; i_++){                                            \
      int c_ = i_ * 256 + tid;                                                 \
      int rt_ = c_ >> 7, kt_ = (c_ >> 6) & 1, ln_ = c_ & 63;                   \
      gload_lds16(Af + (((size_t)(brt + rt_) * 8 + (s) * 2 + kt_) * 64 + ln_) * 8, \
                  (void*)&smem[buf][c_ * 8]);                                  \
      gload_lds16(Bf + (((size_t)(bct + rt_) * 8 + (s) * 2 + kt_) * 64 + ln_) * 8, \
                  (void*)&smem[buf][8192 + c_ * 8]);                           \
    } }while(0)

  f32x4 acc[4][4] = {};
  STAGE(0, 0);
  #pragma unroll
  for (int s = 0; s < 4; s++){
    const int p = s & 1;
    if (s < 3){
      STAGE(p ^ 1, s + 1);
      asm volatile("s_waitcnt vmcnt(8)" ::: "memory");   // stage s landed, s+1 in flight
    } else {
      asm volatile("s_waitcnt vmcnt(0)" ::: "memory");
    }
    __builtin_amdgcn_s_barrier();
    #pragma unroll
    for (int kk = 0; kk < 2; kk++){
      short8 av[4], bv[4];
      #pragma unroll
      for (int m = 0; m < 4; m++)
        av[m] = *reinterpret_cast<const short8*>(&smem[p][(((wm * 4 + m) * 2 + kk) * 64 + lane) * 8]);
      #pragma unroll
      for (int n = 0; n < 4; n++)
        bv[n] = *reinterpret_cast<const short8*>(&smem[p][8192 + (((wn * 4 + n) * 2 + kk) * 64 + lane) * 8]);
      #pragma unroll
      for (int m = 0; m < 4; m++)
        #pragma unroll
        for (int n = 0; n < 4; n++)
          acc[m][n] = __builtin_amdgcn_mfma_f32_16x16x32_bf16(av[m], bv[n], acc[m][n], 0, 0, 0);
    }
    if (s < 3) __syncthreads();   // all reads of buf p done before it is restaged
  }
#undef STAGE

  const int fr = lane & 15, fq = lane >> 4;
  float obv[4];
  #pragma unroll
  for (int n = 0; n < 4; n++){
    const int gcol = bct * 16 + wn * 64 + n * 16 + fr;
    obv[n] = (gcol < NP) ? ob[gcol] : 0.f;
  }

  if (PASS == 0){
    #pragma unroll
    for (int m = 0; m < 4; m++){
      #pragma unroll
      for (int r = 0; r < 4; r++){
        const int grow = brt * 16 + wm * 64 + m * 16 + fq * 4 + r;
        float rsum = 0.f;
        #pragma unroll
        for (int n = 0; n < 4; n++){
          const int gcol = bct * 16 + wn * 64 + n * 16 + fr;
          rsum += (gcol < NP) ? __expf(acc[m][n][r] + obv[n]) : 0.f;
        }
        rsum += __shfl_xor(rsum, 1, 64);
        rsum += __shfl_xor(rsum, 2, 64);
        rsum += __shfl_xor(rsum, 4, 64);
        rsum += __shfl_xor(rsum, 8, 64);
        if (fr == 0 && grow < NN) atomicAdd(&rowsum[grow], rsum);
      }
    }
  } else {
    #pragma unroll
    for (int m = 0; m < 4; m++){
      #pragma unroll
      for (int r = 0; r < 4; r++){
        const int grow = brt * 16 + wm * 64 + m * 16 + fq * 4 + r;
        const bool rv = grow < NN;
        const float ri = rv ? (1.f / rowsum[grow]) : 0.f;
        #pragma unroll
        for (int n = 0; n < 4; n++){
          const int gcol = bct * 16 + wn * 64 + n * 16 + fr;
          if (rv && gcol < NP)
            __builtin_nontemporal_store(ri * __expf(acc[m][n][r] + obv[n]),
                                        &out[(size_t)grow * NP + gcol]);
        }
      }
    }
  }
}

// ---------------- host ----------------
extern "C" void kernel_launch(void* const* d_in, const int* in_sizes, int n_in,
                              void* d_out, int out_size, void* d_ws, size_t ws_size,
                              hipStream_t stream){
  const int*   user_ids = (const int*)d_in[0];
  const int*   prod_ids = (const int*)d_in[1];
  const int*   ei_u     = (const int*)d_in[2];
  const int*   ei_p     = (const int*)d_in[3];
  const float* utab     = (const float*)d_in[4];
  const float* ptab     = (const float*)d_in[5];
  const float* uW       = (const float*)d_in[6];
  const float* ub       = (const float*)d_in[7];
  const float* pW       = (const float*)d_in[8];
  const float* pb       = (const float*)d_in[9];
  const float* oW       = (const float*)d_in[10];
  const float* ob       = (const float*)d_in[11];
  float* out = (float*)d_out;
  (void)in_sizes; (void)n_in; (void)out_size; (void)ws_size;

  char* w = (char*)d_ws;
  size_t off = 0;
  auto alloc = [&](size_t bytes)->void*{
    void* p = w + off; off += (bytes + 255) & ~(size_t)255; return p;
  };
  int*   cnt_u  = (int*)alloc(NN * 4);
  int*   cnt_p  = (int*)alloc(NN * 4);
  float* dinv_u = (float*)alloc(NN * 4);
  float* dinv_p = (float*)alloc(NN * 4);
  int*   ro_u   = (int*)alloc((NN + 1) * 4);
  int*   ro_p   = (int*)alloc((NN + 1) * 4);
  int*   cur_u  = (int*)alloc(NN * 4);
  int*   cur_p  = (int*)alloc(NN * 4);
  int*   col_u  = (int*)alloc((size_t)NE * 4);
  int*   col_p  = (int*)alloc((size_t)NE * 4);
  unsigned short* xu_f  = (unsigned short*)alloc((size_t)NN * DD * 2);
  unsigned short* xp_f  = (unsigned short*)alloc((size_t)NN * DD * 2);
  unsigned short* xu2_f = (unsigned short*)alloc((size_t)NN * DD * 2);
  unsigned short* xp2_f = (unsigned short*)alloc((size_t)NN * DD * 2);
  unsigned short* comb_f= (unsigned short*)alloc((size_t)NRT_PAD * 8 * 64 * 8 * 2);
  unsigned short* hsb  = (unsigned short*)alloc((size_t)NN * DD * 2);
  unsigned short* WuF0 = (unsigned short*)alloc((size_t)DD * DD * 2);
  unsigned short* WuF1 = (unsigned short*)alloc((size_t)DD * DD * 2);
  unsigned short* WpF0 = (unsigned short*)alloc((size_t)DD * DD * 2);
  unsigned short* WpF1 = (unsigned short*)alloc((size_t)DD * DD * 2);
  unsigned short* WoF  = (unsigned short*)alloc((size_t)NCT_PAD * 8 * 64 * 8 * 2);
  float* rowsum = (float*)alloc(NN * 4);

  hipMemsetAsync(cnt_u, 0, NN * 4, stream);
  hipMemsetAsync(cnt_p, 0, NN * 4, stream);
  hipMemsetAsync(rowsum, 0, NN * 4, stream);
  hipMemsetAsync(comb_f, 0, (size_t)NRT_PAD * 8 * 64 * 8 * 2, stream);  // zero pad rowtiles

  const int* src_u = ei_u;  const int* dst_u = ei_u + NE;
  const int* src_p = ei_p;  const int* dst_p = ei_p + NE;

  k_count<<<(NE + 255) / 256, 256, 0, stream>>>(dst_u, cnt_u, NE);
  k_count<<<(NE + 255) / 256, 256, 0, stream>>>(dst_p, cnt_p, NE);
  k_dinv<<<(NN + 255) / 256, 256, 0, stream>>>(cnt_u, dinv_u, NN);
  k_dinv<<<(NN + 255) / 256, 256, 0, stream>>>(cnt_p, dinv_p, NN);
  k_scan<<<1, 1024, 0, stream>>>(cnt_u, ro_u, cur_u, NN);
  k_scan<<<1, 1024, 0, stream>>>(cnt_p, ro_p, cur_p, NN);
  k_fill<<<(NE + 255) / 256, 256, 0, stream>>>(src_u, dst_u, cur_u, col_u, NE);
  k_fill<<<(NE + 255) / 256, 256, 0, stream>>>(src_p, dst_p, cur_p, col_p, NE);

  dim3 gblk(32, 8);
  k_gather_frag<<<NN / 8, gblk, 0, stream>>>(utab, user_ids, xu_f);
  k_gather_frag<<<NN / 8, gblk, 0, stream>>>(ptab, prod_ids, xp_f);

  const int wtotS = DD * DD;
  k_wfrag<<<(wtotS + 255) / 256, 256, 0, stream>>>(uW,                    WuF0, DD, 2, wtotS);
  k_wfrag<<<(wtotS + 255) / 256, 256, 0, stream>>>(uW + (size_t)DD * DD,  WuF1, DD, 2, wtotS);
  k_wfrag<<<(wtotS + 255) / 256, 256, 0, stream>>>(pW,                    WpF0, DD, 2, wtotS);
  k_wfrag<<<(wtotS + 255) / 256, 256, 0, stream>>>(pW + (size_t)DD * DD,  WpF1, DD, 2, wtotS);
  k_wfrag2<<<dim3(316, 8), 256, 0, stream>>>(oW, WoF);

  const int convGrid = (NRT + 3) / 4;   // 313
  dim3 aggBlk(16, 16);
  const int aggGrid = (NN + 15) / 16;

  // layer 1
  k_conv<<<convGrid, 256, 0, stream>>>(xu_f, WuF0, dinv_u, hsb);
  k_agg_frag<<<aggGrid, aggBlk, 0, stream>>>(hsb, dinv_u, ro_u, col_u, ub, xu2_f, 4, 0);
  k_conv<<<convGrid, 256, 0, stream>>>(xp_f, WpF0, dinv_p, hsb);
  k_agg_frag<<<aggGrid, aggBlk, 0, stream>>>(hsb, dinv_p, ro_p, col_p, pb, xp2_f, 4, 0);

  // layer 2 -> comb fragments (user ktiles 0..3, product ktiles 4..7)
  k_conv<<<convGrid, 256, 0, stream>>>(xu2_f, WuF1, dinv_u, hsb);
  k_agg_frag<<<aggGrid, aggBlk, 0, stream>>>(hsb, dinv_u, ro_u, col_u, ub + DD, comb_f, 8, 0);
  k_conv<<<convGrid, 256, 0, stream>>>(xp2_f, WpF1, dinv_p, hsb);
  k_agg_frag<<<aggGrid, aggBlk, 0, stream>>>(hsb, dinv_p, ro_p, col_p, pb + DD, comb_f, 8, 4);

  // two-pass recompute softmax GEMM
  k_big<0><<<NWG_BIG, 256, 0, stream>>>(comb_f, WoF, ob, rowsum, out);
  k_big<1><<<NWG_BIG, 256, 0, stream>>>(comb_f, WoF, ob, rowsum, out);
}

// Round 7
// 722.970 us; speedup vs baseline: 1.7885x; 1.3154x over previous
//
#include <hip/hip_runtime.h>
#include <cstdint>
#include <cstddef>

#define NN 20000      // nodes
#define NE 640000     // edges
#define DD 128        // feature dim
#define NP 10000      // products (output cols)
#define NRT 1250      // NN/16 row-tiles
#define NRT_PAD 1256  // padded rt16 (= 314 row-tiles of 64)
#define NCT_PAD 632   // padded col-tiles of 16 (79 panels of 128)
#define NWG_BIG 474   // 79 col panels x 6 row-range blocks

typedef __attribute__((ext_vector_type(8))) short short8;
typedef __attribute__((ext_vector_type(4))) float f32x4;

static __device__ __forceinline__ unsigned short f2bf(float f){
  uint32_t u = __float_as_uint(f);
  return (unsigned short)((u + 0x7fffu + ((u >> 16) & 1u)) >> 16);
}
static __device__ __forceinline__ float bf2f(unsigned short u){
  return __uint_as_float(((uint32_t)u) << 16);
}

static __device__ __forceinline__ void gload_lds16(const void* g, void* l){
  __builtin_amdgcn_global_load_lds(
      (const __attribute__((address_space(1))) void*)g,
      (__attribute__((address_space(3))) void*)l, 16, 0, 0);
}

// ---------------- CSR build (both graphs per launch) ----------------
__global__ void k_count2(const int* __restrict__ dst_u, const int* __restrict__ dst_p,
                         int* __restrict__ cnt){   // cnt[2*NN]
  int i = blockIdx.x * blockDim.x + threadIdx.x;
  if (i < NE) atomicAdd(&cnt[dst_u[i]], 1);
  else if (i < 2 * NE) atomicAdd(&cnt[NN + dst_p[i - NE]], 1);
}

__global__ void k_dinv2(const int* __restrict__ cnt, float* __restrict__ dinv){ // [2*NN]
  int i = blockIdx.x * blockDim.x + threadIdx.x;
  if (i < 2 * NN) dinv[i] = rsqrtf((float)(cnt[i] + 1));  // +1 self-loop
}

// 2 blocks: block b scans graph b
__global__ void k_scan2(const int* __restrict__ cnt, int* __restrict__ row_off,
                        int* __restrict__ cursor){
  __shared__ int part[1024];
  const int g = blockIdx.x;
  const int* c = cnt + g * NN;
  int* ro = row_off + g * (NN + 1);
  int* cur = cursor + g * NN;
  int t = threadIdx.x;
  int per = (NN + 1023) >> 10;
  int base = t * per;
  int s = 0;
  for (int i = 0; i < per; i++){ int idx = base + i; if (idx < NN) s += c[idx]; }
  part[t] = s;
  __syncthreads();
  for (int off = 1; off < 1024; off <<= 1){
    int v = (t >= off) ? part[t - off] : 0;
    __syncthreads();
    part[t] += v;
    __syncthreads();
  }
  int run = (t == 0) ? 0 : part[t - 1];
  for (int i = 0; i < per; i++){
    int idx = base + i;
    if (idx < NN){ ro[idx] = run; cur[idx] = run; run += c[idx]; }
  }
  if (t == 0) ro[NN] = part[1023];
}

__global__ void k_fill2(const int* __restrict__ src_u, const int* __restrict__ dst_u,
                        const int* __restrict__ src_p, const int* __restrict__ dst_p,
                        int* __restrict__ cursor, int* __restrict__ col){ // col[2*NE]
  int i = blockIdx.x * blockDim.x + threadIdx.x;
  if (i < NE){
    int p = atomicAdd(&cursor[dst_u[i]], 1);
    col[p] = src_u[i];
  } else if (i < 2 * NE){
    int j = i - NE;
    int p = atomicAdd(&cursor[NN + dst_p[j]], 1);
    col[NE + p] = src_p[j];
  }
}

// ---------------- packers (MFMA fragment order) ----------------
// frag layout: chunk[(rowtile16*KT + ktile)*64 + k8*16 + fr][e]
//   holds X[rowtile16*16 + fr][ktile*32 + k8*8 + e], chunk = 8 bf16 = 16B

__global__ void k_gather2(const float* __restrict__ utab, const int* __restrict__ uids,
                          const float* __restrict__ ptab, const int* __restrict__ pids,
                          unsigned short* __restrict__ xu, unsigned short* __restrict__ xp){
  const float* tab = blockIdx.y ? ptab : utab;
  const int*   ids = blockIdx.y ? pids : uids;
  unsigned short* xf = blockIdx.y ? xp : xu;
  int node = blockIdx.x * blockDim.y + threadIdx.y;
  int tx = threadIdx.x;            // covers d = tx*4 .. tx*4+3
  if (node >= NN) return;
  const float4 v = *reinterpret_cast<const float4*>(tab + (size_t)ids[node] * DD + tx * 4);
  ushort4 o; o.x = f2bf(v.x); o.y = f2bf(v.y); o.z = f2bf(v.z); o.w = f2bf(v.w);
  size_t chunk = ((size_t)(node >> 4) * 4 + (tx >> 3)) * 64 + ((tx >> 1) & 3) * 16 + (node & 15);
  *reinterpret_cast<ushort4*>(xf + chunk * 8 + (tx & 1) * 4) = o;
}

// 4 small conv weights in one launch (blockIdx.y picks)
__global__ void k_wfrag4(const float* __restrict__ uW, const float* __restrict__ pW,
                         unsigned short* __restrict__ WuF0, unsigned short* __restrict__ WuF1,
                         unsigned short* __restrict__ WpF0, unsigned short* __restrict__ WpF1){
  const float* W; unsigned short* Wf;
  switch (blockIdx.y){
    case 0: W = uW;                    Wf = WuF0; break;
    case 1: W = uW + (size_t)DD * DD;  Wf = WuF1; break;
    case 2: W = pW;                    Wf = WpF0; break;
    default:W = pW + (size_t)DD * DD;  Wf = WpF1; break;
  }
  int i = blockIdx.x * blockDim.x + threadIdx.x;
  if (i >= DD * DD) return;
  int e = i & 7, l = (i >> 3) & 63, rem = i >> 9;
  int kt = rem & 3, ct = rem >> 2;
  int col = ct * 16 + (l & 15);
  int k = kt * 32 + (l >> 4) * 8 + e;
  Wf[i] = f2bf(W[(size_t)k * DD + col]);
}

// big weight oW [256][NP] f32 -> frag order bf16, via LDS transpose tile.
__global__ __launch_bounds__(256) void k_wfrag2(const float* __restrict__ W,
                                                unsigned short* __restrict__ Wf){
  __shared__ float tile[32][33];
  const int kb = blockIdx.y * 32, cb = blockIdx.x * 32;
  const int tx = threadIdx.x & 31, ty = threadIdx.x >> 5;   // ty 0..7
  const int col = cb + tx;
  #pragma unroll
  for (int j = 0; j < 4; j++){
    int k = ty + j * 8;
    tile[k][tx] = (col < NP) ? W[(size_t)(kb + k) * NP + col] : 0.f;
  }
  __syncthreads();
  const int t = threadIdx.x;
  const int ct2 = t >> 7, rep = t & 1, l = (t >> 1) & 63;
  const int c_loc = ct2 * 16 + (l & 15);
  const int k_loc = (l >> 4) * 8 + rep * 4;
  ushort4 o;
  o.x = f2bf(tile[k_loc + 0][c_loc]);
  o.y = f2bf(tile[k_loc + 1][c_loc]);
  o.z = f2bf(tile[k_loc + 2][c_loc]);
  o.w = f2bf(tile[k_loc + 3][c_loc]);
  const int ct = cb / 16 + ct2, kt = kb / 32;
  *reinterpret_cast<ushort4*>(Wf + ((size_t)(ct * 8 + kt) * 64 + l) * 8 + rep * 4) = o;
}

// ---------------- conv GEMM both towers: hsb = bf16(dinv * (x @ W)) ----------------
__global__ __launch_bounds__(256) void k_conv2(
        const unsigned short* __restrict__ Au, const unsigned short* __restrict__ Ap,
        const unsigned short* __restrict__ Wu, const unsigned short* __restrict__ Wp,
        const float* __restrict__ du, const float* __restrict__ dp,
        unsigned short* __restrict__ hu, unsigned short* __restrict__ hp){
  const unsigned short* Af = blockIdx.y ? Ap : Au;
  const unsigned short* Wf = blockIdx.y ? Wp : Wu;
  const float* dinv        = blockIdx.y ? dp : du;
  unsigned short* hsb      = blockIdx.y ? hp : hu;
  int gw = blockIdx.x * 4 + (threadIdx.x >> 6);
  int lane = threadIdx.x & 63;
  bool valid = gw < NRT;
  int R = valid ? gw : (NRT - 1);
  short8 a[4];
  #pragma unroll
  for (int kt = 0; kt < 4; kt++)
    a[kt] = *reinterpret_cast<const short8*>(Af + ((size_t)(R * 4 + kt) * 64 + lane) * 8);
  int fr = lane & 15, fq = lane >> 4;
  #pragma unroll
  for (int ct = 0; ct < 8; ct++){
    f32x4 acc = {0.f, 0.f, 0.f, 0.f};
    #pragma unroll
    for (int kt = 0; kt < 4; kt++){
      short8 b = *reinterpret_cast<const short8*>(Wf + ((size_t)(ct * 4 + kt) * 64 + lane) * 8);
      acc = __builtin_amdgcn_mfma_f32_16x16x32_bf16(a[kt], b, acc, 0, 0, 0);
    }
    if (valid){
      #pragma unroll
      for (int r = 0; r < 4; r++){
        int grow = R * 16 + fq * 4 + r;
        hsb[(size_t)grow * DD + ct * 16 + fr] = f2bf(dinv[grow] * acc[r]);
      }
    }
  }
}

// ---------------- aggregation both towers (bf16 hs) -> frag bf16 ----------------
// block (16,16): 16 lanes per node, each lane owns 8 dims = 1 frag chunk.
__global__ void k_agg2(const unsigned short* __restrict__ hu, const unsigned short* __restrict__ hp,
                       const float* __restrict__ du, const float* __restrict__ dp,
                       const int* __restrict__ ro, const int* __restrict__ colb,
                       const float* __restrict__ bu, const float* __restrict__ bp,
                       unsigned short* __restrict__ xfu, unsigned short* __restrict__ xfp,
                       int KT, int toff_p){
  const int g = blockIdx.y;
  const unsigned short* hsb = g ? hp : hu;
  const float* dinv = g ? (dp + NN) - NN : du;   // dinv arrays passed separately
  const float* dv   = g ? dp : du;
  const float* bias = g ? bp : bu;
  unsigned short* xf = g ? xfp : xfu;
  const int* row_off = ro + g * (NN + 1);
  const int* col     = colb + (size_t)g * NE;
  const int toff = g ? toff_p : 0;
  (void)dinv;

  int node = blockIdx.x * blockDim.y + threadIdx.y;
  int tx = threadIdx.x;   // 0..15; dims tx*8..tx*8+7
  if (node >= NN) return;
  const short8* h8 = reinterpret_cast<const short8*>(hsb);
  float a[8];
  {
    short8 v = h8[(size_t)node * 16 + tx];
    #pragma unroll
    for (int j = 0; j < 8; j++) a[j] = bf2f((unsigned short)v[j]);
  }
  int s = row_off[node], e = row_off[node + 1];
  int i = s;
  for (; i + 1 < e; i += 2){
    short8 v0 = h8[(size_t)col[i] * 16 + tx];
    short8 v1 = h8[(size_t)col[i + 1] * 16 + tx];
    #pragma unroll
    for (int j = 0; j < 8; j++) a[j] += bf2f((unsigned short)v0[j]) + bf2f((unsigned short)v1[j]);
  }
  if (i < e){
    short8 v = h8[(size_t)col[i] * 16 + tx];
    #pragma unroll
    for (int j = 0; j < 8; j++) a[j] += bf2f((unsigned short)v[j]);
  }
  float dn = dv[node];
  short8 ov;
  #pragma unroll
  for (int j = 0; j < 8; j++)
    ov[j] = (short)f2bf(dn * a[j] + bias[tx * 8 + j]);
  size_t chunk = ((size_t)(node >> 4) * KT + toff + (tx >> 2)) * 64 + (tx & 3) * 16 + (node & 15);
  *reinterpret_cast<short8*>(xf + chunk * 8) = ov;
}

// ---------------- big GEMM v3: B-stationary, B-in-regs, A via LDS dbuf ----------------
// grid 474 = 79 col-panels x 6 row-range blocks, all co-resident (2/CU).
// Per wave: B slice (64 cols x 256 K) resident in 128 VGPR; A 64-row tiles staged
// to LDS (32 KB dbuf), counted vmcnt(8). PASS 0: rowsum atomics. PASS 1: out stores.
template<int PASS>
__global__ __launch_bounds__(256, 2) void k_big(
    const unsigned short* __restrict__ Af, const unsigned short* __restrict__ Bf,
    const float* __restrict__ ob, float* __restrict__ rowsum, float* __restrict__ out){
  __shared__ unsigned short sA[2][16384];   // 2 x 32KB (one 64-row x 256-K tile)
  const int tid = threadIdx.x, lane = tid & 63, wid = tid >> 6;
  const int wm = wid >> 1, wn = wid & 1;
  const int fr = lane & 15, fq = lane >> 4;

  // bijective XCD chunking: 474 = 8*59 + 2
  const int orig = blockIdx.x;
  const int xcd = orig & 7, pos = orig >> 3;
  const int wgid = (xcd < 2 ? xcd * 60 : 120 + (xcd - 2) * 59) + pos;
  const int cp = wgid / 6, six = wgid - cp * 6;
  const int rt0 = six * 52 + (six < 2 ? six : 2);     // row-tile-of-64 start
  const int nrt = 52 + (six < 2 ? 1 : 0);             // 53,53,52,52,52,52 -> 314
  const int bct = cp * 8;

  // B regs: wave's 4 col-tiles x 8 k-tiles
  short8 breg[4][8];
  #pragma unroll
  for (int n = 0; n < 4; n++)
    #pragma unroll
    for (int kt = 0; kt < 8; kt++)
      breg[n][kt] = *reinterpret_cast<const short8*>(
          Bf + (((size_t)(bct + wn * 4 + n) * 8 + kt) * 64 + lane) * 8);

  float obv[4];
  #pragma unroll
  for (int n = 0; n < 4; n++){
    int gcol = cp * 128 + wn * 64 + n * 16 + fr;
    obv[n] = (gcol < NP) ? ob[gcol] : 0.f;
  }

#define STAGEA(buf, rt) do{                                                    \
    _Pragma("unroll")                                                          \
    for (int i_ = 0; i_ < 8; i_++){                                            \
      int c_ = i_ * 256 + tid;                                                 \
      gload_lds16(Af + ((size_t)(rt) * 2048 + c_) * 8, (void*)&sA[buf][c_ * 8]); \
    } }while(0)

  STAGEA(0, rt0);
  for (int t = 0; t < nrt; t++){
    const int p = t & 1;
    if (t + 1 < nrt){
      STAGEA(p ^ 1, rt0 + t + 1);
      asm volatile("s_waitcnt vmcnt(8)" ::: "memory");   // tile t landed, t+1 in flight
    } else {
      asm volatile("s_waitcnt vmcnt(0)" ::: "memory");
    }
    __builtin_amdgcn_s_barrier();

    f32x4 acc[2][4] = {};
    #pragma unroll
    for (int m = 0; m < 2; m++)
      #pragma unroll
      for (int kt = 0; kt < 8; kt++){
        short8 a = *reinterpret_cast<const short8*>(
            &sA[p][(((wm * 2 + m) * 8 + kt) * 64 + lane) * 8]);
        #pragma unroll
        for (int n = 0; n < 4; n++)
          acc[m][n] = __builtin_amdgcn_mfma_f32_16x16x32_bf16(a, breg[n][kt], acc[m][n], 0, 0, 0);
      }
    __builtin_amdgcn_s_barrier();

    const int rbase = (rt0 + t) * 64 + wm * 32;
    if (PASS == 0){
      #pragma unroll
      for (int m = 0; m < 2; m++)
        #pragma unroll
        for (int r = 0; r < 4; r++){
          const int grow = rbase + m * 16 + fq * 4 + r;
          float rs = 0.f;
          #pragma unroll
          for (int n = 0; n < 4; n++){
            const int gcol = cp * 128 + wn * 64 + n * 16 + fr;
            rs += (gcol < NP) ? __expf(acc[m][n][r] + obv[n]) : 0.f;
          }
          rs += __shfl_xor(rs, 1, 64);
          rs += __shfl_xor(rs, 2, 64);
          rs += __shfl_xor(rs, 4, 64);
          rs += __shfl_xor(rs, 8, 64);
          if (fr == 0 && grow < NN) atomicAdd(&rowsum[grow], rs);
        }
    } else {
      #pragma unroll
      for (int m = 0; m < 2; m++)
        #pragma unroll
        for (int r = 0; r < 4; r++){
          const int grow = rbase + m * 16 + fq * 4 + r;
          const bool rv = grow < NN;
          const float ri = rv ? 1.f / rowsum[grow] : 0.f;
          #pragma unroll
          for (int n = 0; n < 4; n++){
            const int gcol = cp * 128 + wn * 64 + n * 16 + fr;
            if (rv && gcol < NP)
              __builtin_nontemporal_store(ri * __expf(acc[m][n][r] + obv[n]),
                                          &out[(size_t)grow * NP + gcol]);
          }
        }
    }
  }
#undef STAGEA
}

// ---------------- host ----------------
extern "C" void kernel_launch(void* const* d_in, const int* in_sizes, int n_in,
                              void* d_out, int out_size, void* d_ws, size_t ws_size,
                              hipStream_t stream){
  const int*   user_ids = (const int*)d_in[0];
  const int*   prod_ids = (const int*)d_in[1];
  const int*   ei_u     = (const int*)d_in[2];
  const int*   ei_p     = (const int*)d_in[3];
  const float* utab     = (const float*)d_in[4];
  const float* ptab     = (const float*)d_in[5];
  const float* uW       = (const float*)d_in[6];
  const float* ub       = (const float*)d_in[7];
  const float* pW       = (const float*)d_in[8];
  const float* pb       = (const float*)d_in[9];
  const float* oW       = (const float*)d_in[10];
  const float* ob       = (const float*)d_in[11];
  float* out = (float*)d_out;
  (void)in_sizes; (void)n_in; (void)out_size; (void)ws_size;

  char* w = (char*)d_ws;
  size_t off = 0;
  auto alloc = [&](size_t bytes)->void*{
    void* p = w + off; off += (bytes + 255) & ~(size_t)255; return p;
  };
  // cnt(2NN) and rowsum(NN) contiguous -> single memset (2NN*4 = 160000 is 256-aligned)
  int*   cnt    = (int*)alloc(2 * NN * 4);
  float* rowsum = (float*)alloc(NN * 4);
  float* dinv   = (float*)alloc(2 * NN * 4);     // [u | p]
  int*   ro     = (int*)alloc(2 * (NN + 1) * 4); // [u | p]
  int*   cur    = (int*)alloc(2 * NN * 4);
  int*   colb   = (int*)alloc((size_t)2 * NE * 4);
  unsigned short* xu_f  = (unsigned short*)alloc((size_t)NN * DD * 2);
  unsigned short* xp_f  = (unsigned short*)alloc((size_t)NN * DD * 2);
  unsigned short* xu2_f = (unsigned short*)alloc((size_t)NN * DD * 2);
  unsigned short* xp2_f = (unsigned short*)alloc((size_t)NN * DD * 2);
  unsigned short* comb_f= (unsigned short*)alloc((size_t)NRT_PAD * 8 * 64 * 8 * 2);
  unsigned short* hu    = (unsigned short*)alloc((size_t)NN * DD * 2);
  unsigned short* hp    = (unsigned short*)alloc((size_t)NN * DD * 2);
  unsigned short* WuF0 = (unsigned short*)alloc((size_t)DD * DD * 2);
  unsigned short* WuF1 = (unsigned short*)alloc((size_t)DD * DD * 2);
  unsigned short* WpF0 = (unsigned short*)alloc((size_t)DD * DD * 2);
  unsigned short* WpF1 = (unsigned short*)alloc((size_t)DD * DD * 2);
  unsigned short* WoF  = (unsigned short*)alloc((size_t)NCT_PAD * 8 * 64 * 8 * 2);

  hipMemsetAsync(cnt, 0, (2 * NN + NN) * 4, stream);             // cnt + rowsum
  hipMemsetAsync(comb_f + (size_t)NRT * 8 * 64 * 8, 0,
                 (size_t)(NRT_PAD - NRT) * 8 * 64 * 8 * 2, stream);  // pad rows only

  const int* src_u = ei_u;  const int* dst_u = ei_u + NE;
  const int* src_p = ei_p;  const int* dst_p = ei_p + NE;

  k_count2<<<(2 * NE + 255) / 256, 256, 0, stream>>>(dst_u, dst_p, cnt);
  k_dinv2<<<(2 * NN + 255) / 256, 256, 0, stream>>>(cnt, dinv);
  k_scan2<<<2, 1024, 0, stream>>>(cnt, ro, cur);
  k_fill2<<<(2 * NE + 255) / 256, 256, 0, stream>>>(src_u, dst_u, src_p, dst_p, cur, colb);

  dim3 gblk(32, 8);
  k_gather2<<<dim3(NN / 8, 2), gblk, 0, stream>>>(utab, user_ids, ptab, prod_ids, xu_f, xp_f);

  k_wfrag4<<<dim3(64, 4), 256, 0, stream>>>(uW, pW, WuF0, WuF1, WpF0, WpF1);
  k_wfrag2<<<dim3(316, 8), 256, 0, stream>>>(oW, WoF);

  const int convGrid = (NRT + 3) / 4;   // 313
  dim3 aggBlk(16, 16);
  const int aggGrid = (NN + 15) / 16;

  // layer 1 (both towers per launch)
  k_conv2<<<dim3(convGrid, 2), 256, 0, stream>>>(xu_f, xp_f, WuF0, WpF0,
                                                 dinv, dinv + NN, hu, hp);
  k_agg2<<<dim3(aggGrid, 2), aggBlk, 0, stream>>>(hu, hp, dinv, dinv + NN, ro, colb,
                                                  ub, pb, xu2_f, xp2_f, 4, 0);
  // layer 2 -> comb fragments (user ktiles 0..3, product ktiles 4..7)
  k_conv2<<<dim3(convGrid, 2), 256, 0, stream>>>(xu2_f, xp2_f, WuF1, WpF1,
                                                 dinv, dinv + NN, hu, hp);
  k_agg2<<<dim3(aggGrid, 2), aggBlk, 0, stream>>>(hu, hp, dinv, dinv + NN, ro, colb,
                                                  ub + DD, pb + DD, comb_f, comb_f, 8, 4);

  // two-pass recompute softmax GEMM (B-stationary)
  k_big<0><<<NWG_BIG, 256, 0, stream>>>(comb_f, WoF, ob, rowsum, out);
  k_big<1><<<NWG_BIG, 256, 0, stream>>>(comb_f, WoF, ob, rowsum, out);
}

// Round 8
// 704.792 us; speedup vs baseline: 1.8346x; 1.0258x over previous
//
#include <hip/hip_runtime.h>
#include <cstdint>
#include <cstddef>

#define NN 20000      // nodes
#define NE 640000     // edges
#define DD 128        // feature dim
#define NP 10000      // products (output cols)
#define NRT 1250      // NN/16 row-tiles
#define NRT_PAD 1256  // padded rt16 (= 314 row-tiles of 64)
#define NCT_PAD 632   // padded col-tiles of 16 (79 panels of 128)
#define NWG_BIG 474   // 79 col panels x 6 row-range blocks

typedef __attribute__((ext_vector_type(8))) short short8;
typedef __attribute__((ext_vector_type(4))) float f32x4;

static __device__ __forceinline__ unsigned short f2bf(float f){
  uint32_t u = __float_as_uint(f);
  return (unsigned short)((u + 0x7fffu + ((u >> 16) & 1u)) >> 16);
}
static __device__ __forceinline__ float bf2f(unsigned short u){
  return __uint_as_float(((uint32_t)u) << 16);
}

static __device__ __forceinline__ void gload_lds16(const void* g, void* l){
  __builtin_amdgcn_global_load_lds(
      (const __attribute__((address_space(1))) void*)g,
      (__attribute__((address_space(3))) void*)l, 16, 0, 0);
}

// ---------------- mega-prologue: count + gather(frag) + all weight packers ----------------
// block ranges: [0,5000) count | [5000,10000) gather | [10000,10256) wfrag4 | [10256,12784) wfrag2
#define PREP_NWG 12784
__global__ __launch_bounds__(256) void k_prep(
    const int* __restrict__ dst_u, const int* __restrict__ dst_p, int* __restrict__ cnt,
    const float* __restrict__ utab, const int* __restrict__ uids,
    const float* __restrict__ ptab, const int* __restrict__ pids,
    unsigned short* __restrict__ xu, unsigned short* __restrict__ xp,
    const float* __restrict__ uW, const float* __restrict__ pW,
    unsigned short* __restrict__ WuF0, unsigned short* __restrict__ WuF1,
    unsigned short* __restrict__ WpF0, unsigned short* __restrict__ WpF1,
    const float* __restrict__ oW, unsigned short* __restrict__ WoF){
  __shared__ float tile[32][33];
  const int b = blockIdx.x, tid = threadIdx.x;

  if (b < 5000){                      // degree count, both graphs
    int i = b * 256 + tid;
    if (i < NE) atomicAdd(&cnt[dst_u[i]], 1);
    else atomicAdd(&cnt[NN + dst_p[i - NE]], 1);

  } else if (b < 10000){              // embedding gather -> frag order
    int bg = b - 5000;
    int tower = bg / 2500, nb = bg % 2500;
    const float* tab = tower ? ptab : utab;
    const int*   ids = tower ? pids : uids;
    unsigned short* xf = tower ? xp : xu;
    int tx = tid & 31, ny = tid >> 5;
    int node = nb * 8 + ny;
    const float4 v = *reinterpret_cast<const float4*>(tab + (size_t)ids[node] * DD + tx * 4);
    ushort4 o; o.x = f2bf(v.x); o.y = f2bf(v.y); o.z = f2bf(v.z); o.w = f2bf(v.w);
    size_t chunk = ((size_t)(node >> 4) * 4 + (tx >> 3)) * 64 + ((tx >> 1) & 3) * 16 + (node & 15);
    *reinterpret_cast<ushort4*>(xf + chunk * 8 + (tx & 1) * 4) = o;

  } else if (b < 10256){              // 4 small conv weights -> frag order
    int bw = b - 10000;
    int wy = bw >> 6, bx = bw & 63;
    const float* W; unsigned short* Wf;
    switch (wy){
      case 0: W = uW;                   Wf = WuF0; break;
      case 1: W = uW + (size_t)DD * DD; Wf = WuF1; break;
      case 2: W = pW;                   Wf = WpF0; break;
      default:W = pW + (size_t)DD * DD; Wf = WpF1; break;
    }
    int i = bx * 256 + tid;
    int e = i & 7, l = (i >> 3) & 63, rem = i >> 9;
    int kt = rem & 3, ct = rem >> 2;
    int col = ct * 16 + (l & 15);
    int k = kt * 32 + (l >> 4) * 8 + e;
    Wf[i] = f2bf(W[(size_t)k * DD + col]);

  } else {                            // big weight oW [256][NP] -> frag order (LDS transpose)
    int bw = b - 10256;
    int bx = bw % 316, by = bw / 316;
    const int kb = by * 32, cb = bx * 32;
    const int tx = tid & 31, ty = tid >> 5;
    const int col = cb + tx;
    #pragma unroll
    for (int j = 0; j < 4; j++){
      int k = ty + j * 8;
      tile[k][tx] = (col < NP) ? oW[(size_t)(kb + k) * NP + col] : 0.f;
    }
    __syncthreads();
    const int ct2 = tid >> 7, rep = tid & 1, l = (tid >> 1) & 63;
    const int c_loc = ct2 * 16 + (l & 15);
    const int k_loc = (l >> 4) * 8 + rep * 4;
    ushort4 o;
    o.x = f2bf(tile[k_loc + 0][c_loc]);
    o.y = f2bf(tile[k_loc + 1][c_loc]);
    o.z = f2bf(tile[k_loc + 2][c_loc]);
    o.w = f2bf(tile[k_loc + 3][c_loc]);
    const int ct = cb / 16 + ct2, kt = kb / 32;
    *reinterpret_cast<ushort4*>(WoF + ((size_t)(ct * 8 + kt) * 64 + l) * 8 + rep * 4) = o;
  }
}

// ---------------- scan (+dinv fused): 2 blocks, block g scans graph g ----------------
__global__ void k_scan2(const int* __restrict__ cnt, int* __restrict__ row_off,
                        int* __restrict__ cursor, float* __restrict__ dinv){
  __shared__ int part[1024];
  const int g = blockIdx.x;
  const int* c = cnt + g * NN;
  int* ro = row_off + g * (NN + 1);
  int* cur = cursor + g * NN;
  float* dv = dinv + g * NN;
  int t = threadIdx.x;
  int per = (NN + 1023) >> 10;
  int base = t * per;
  int s = 0;
  for (int i = 0; i < per; i++){
    int idx = base + i;
    if (idx < NN){
      int cv = c[idx];
      dv[idx] = rsqrtf((float)(cv + 1));   // +1 self-loop
      s += cv;
    }
  }
  part[t] = s;
  __syncthreads();
  for (int off = 1; off < 1024; off <<= 1){
    int v = (t >= off) ? part[t - off] : 0;
    __syncthreads();
    part[t] += v;
    __syncthreads();
  }
  int run = (t == 0) ? 0 : part[t - 1];
  for (int i = 0; i < per; i++){
    int idx = base + i;
    if (idx < NN){ ro[idx] = run; cur[idx] = run; run += c[idx]; }
  }
  if (t == 0) ro[NN] = part[1023];
}

__global__ void k_fill2(const int* __restrict__ src_u, const int* __restrict__ dst_u,
                        const int* __restrict__ src_p, const int* __restrict__ dst_p,
                        int* __restrict__ cursor, int* __restrict__ col){ // col[2*NE]
  int i = blockIdx.x * blockDim.x + threadIdx.x;
  if (i < NE){
    int p = atomicAdd(&cursor[dst_u[i]], 1);
    col[p] = src_u[i];
  } else if (i < 2 * NE){
    int j = i - NE;
    int p = atomicAdd(&cursor[NN + dst_p[j]], 1);
    col[NE + p] = src_p[j];
  }
}

// ---------------- conv GEMM both towers: hsb = bf16(dinv * (x @ W)) ----------------
__global__ __launch_bounds__(256) void k_conv2(
        const unsigned short* __restrict__ Au, const unsigned short* __restrict__ Ap,
        const unsigned short* __restrict__ Wu, const unsigned short* __restrict__ Wp,
        const float* __restrict__ du, const float* __restrict__ dp,
        unsigned short* __restrict__ hu, unsigned short* __restrict__ hp){
  const unsigned short* Af = blockIdx.y ? Ap : Au;
  const unsigned short* Wf = blockIdx.y ? Wp : Wu;
  const float* dinv        = blockIdx.y ? dp : du;
  unsigned short* hsb      = blockIdx.y ? hp : hu;
  int gw = blockIdx.x * 4 + (threadIdx.x >> 6);
  int lane = threadIdx.x & 63;
  bool valid = gw < NRT;
  int R = valid ? gw : (NRT - 1);
  short8 a[4];
  #pragma unroll
  for (int kt = 0; kt < 4; kt++)
    a[kt] = *reinterpret_cast<const short8*>(Af + ((size_t)(R * 4 + kt) * 64 + lane) * 8);
  int fr = lane & 15, fq = lane >> 4;
  #pragma unroll
  for (int ct = 0; ct < 8; ct++){
    f32x4 acc = {0.f, 0.f, 0.f, 0.f};
    #pragma unroll
    for (int kt = 0; kt < 4; kt++){
      short8 b = *reinterpret_cast<const short8*>(Wf + ((size_t)(ct * 4 + kt) * 64 + lane) * 8);
      acc = __builtin_amdgcn_mfma_f32_16x16x32_bf16(a[kt], b, acc, 0, 0, 0);
    }
    if (valid){
      #pragma unroll
      for (int r = 0; r < 4; r++){
        int grow = R * 16 + fq * 4 + r;
        hsb[(size_t)grow * DD + ct * 16 + fr] = f2bf(dinv[grow] * acc[r]);
      }
    }
  }
}

// ---------------- aggregation both towers (bf16 hs) -> frag bf16, 4-deep MLP ----------------
__global__ void k_agg2(const unsigned short* __restrict__ hu, const unsigned short* __restrict__ hp,
                       const float* __restrict__ du, const float* __restrict__ dp,
                       const int* __restrict__ ro, const int* __restrict__ colb,
                       const float* __restrict__ bu, const float* __restrict__ bp,
                       unsigned short* __restrict__ xfu, unsigned short* __restrict__ xfp,
                       int KT, int toff_p){
  const int g = blockIdx.y;
  const unsigned short* hsb = g ? hp : hu;
  const float* dv   = g ? dp : du;
  const float* bias = g ? bp : bu;
  unsigned short* xf = g ? xfp : xfu;
  const int* row_off = ro + g * (NN + 1);
  const int* col     = colb + (size_t)g * NE;
  const int toff = g ? toff_p : 0;

  int node = blockIdx.x * blockDim.y + threadIdx.y;
  int tx = threadIdx.x;   // 0..15; dims tx*8..tx*8+7
  if (node >= NN) return;
  const short8* h8 = reinterpret_cast<const short8*>(hsb);
  float a[8];
  {
    short8 v = h8[(size_t)node * 16 + tx];
    #pragma unroll
    for (int j = 0; j < 8; j++) a[j] = bf2f((unsigned short)v[j]);
  }
  int s = row_off[node], e = row_off[node + 1];
  int i = s;
  for (; i + 3 < e; i += 4){
    short8 v0 = h8[(size_t)col[i] * 16 + tx];
    short8 v1 = h8[(size_t)col[i + 1] * 16 + tx];
    short8 v2 = h8[(size_t)col[i + 2] * 16 + tx];
    short8 v3 = h8[(size_t)col[i + 3] * 16 + tx];
    #pragma unroll
    for (int j = 0; j < 8; j++)
      a[j] += (bf2f((unsigned short)v0[j]) + bf2f((unsigned short)v1[j]))
            + (bf2f((unsigned short)v2[j]) + bf2f((unsigned short)v3[j]));
  }
  for (; i < e; i++){
    short8 v = h8[(size_t)col[i] * 16 + tx];
    #pragma unroll
    for (int j = 0; j < 8; j++) a[j] += bf2f((unsigned short)v[j]);
  }
  float dn = dv[node];
  short8 ov;
  #pragma unroll
  for (int j = 0; j < 8; j++)
    ov[j] = (short)f2bf(dn * a[j] + bias[tx * 8 + j]);
  size_t chunk = ((size_t)(node >> 4) * KT + toff + (tx >> 2)) * 64 + (tx & 3) * 16 + (node & 15);
  *reinterpret_cast<short8*>(xf + chunk * 8) = ov;
}

// ---------------- big GEMM v3: B-stationary, B-in-regs, A via LDS dbuf ----------------
// grid 474 = 79 col-panels x 6 row-range blocks, 2 blocks/CU.
// PASS 0: rowsum atomics (no stores). PASS 1: out = exp/rowsum, full-line nt stores.
template<int PASS>
__global__ __launch_bounds__(256, 2) void k_big(
    const unsigned short* __restrict__ Af, const unsigned short* __restrict__ Bf,
    const float* __restrict__ ob, float* __restrict__ rowsum, float* __restrict__ out){
  __shared__ unsigned short sA[2][16384];   // 2 x 32KB (one 64-row x 256-K tile)
  const int tid = threadIdx.x, lane = tid & 63, wid = tid >> 6;
  const int wm = wid >> 1, wn = wid & 1;
  const int fr = lane & 15, fq = lane >> 4;

  // bijective XCD chunking: 474 = 8*59 + 2
  const int orig = blockIdx.x;
  const int xcd = orig & 7, pos = orig >> 3;
  const int wgid = (xcd < 2 ? xcd * 60 : 120 + (xcd - 2) * 59) + pos;
  const int cp = wgid / 6, six = wgid - cp * 6;
  const int rt0 = six * 52 + (six < 2 ? six : 2);     // row-tile-of-64 start
  const int nrt = 52 + (six < 2 ? 1 : 0);             // 53,53,52,52,52,52 -> 314
  const int bct = cp * 8;

  // B regs: wave's 4 col-tiles x 8 k-tiles (128 VGPR)
  short8 breg[4][8];
  #pragma unroll
  for (int n = 0; n < 4; n++)
    #pragma unroll
    for (int kt = 0; kt < 8; kt++)
      breg[n][kt] = *reinterpret_cast<const short8*>(
          Bf + (((size_t)(bct + wn * 4 + n) * 8 + kt) * 64 + lane) * 8);

  float obv[4];
  #pragma unroll
  for (int n = 0; n < 4; n++){
    int gcol = cp * 128 + wn * 64 + n * 16 + fr;
    obv[n] = (gcol < NP) ? ob[gcol] : 0.f;
  }

#define STAGEA(buf, rt) do{                                                    \
    _Pragma("unroll")                                                          \
    for (int i_ = 0; i_ < 8; i_++){                                            \
      int c_ = i_ * 256 + tid;                                                 \
      gload_lds16(Af + ((size_t)(rt) * 2048 + c_) * 8, (void*)&sA[buf][c_ * 8]); \
    } }while(0)

  STAGEA(0, rt0);
  for (int t = 0; t < nrt; t++){
    const int p = t & 1;
    if (t + 1 < nrt){
      STAGEA(p ^ 1, rt0 + t + 1);
      asm volatile("s_waitcnt vmcnt(8)" ::: "memory");   // tile t landed, t+1 in flight
    } else {
      asm volatile("s_waitcnt vmcnt(0)" ::: "memory");
    }
    __builtin_amdgcn_s_barrier();

    f32x4 acc[2][4] = {};
    __builtin_amdgcn_s_setprio(1);
    #pragma unroll
    for (int m = 0; m < 2; m++)
      #pragma unroll
      for (int kt = 0; kt < 8; kt++){
        short8 a = *reinterpret_cast<const short8*>(
            &sA[p][(((wm * 2 + m) * 8 + kt) * 64 + lane) * 8]);
        #pragma unroll
        for (int n = 0; n < 4; n++)
          acc[m][n] = __builtin_amdgcn_mfma_f32_16x16x32_bf16(a, breg[n][kt], acc[m][n], 0, 0, 0);
      }
    __builtin_amdgcn_s_setprio(0);
    __builtin_amdgcn_s_barrier();

    const int rbase = (rt0 + t) * 64 + wm * 32;
    if (PASS == 0){
      #pragma unroll
      for (int m = 0; m < 2; m++)
        #pragma unroll
        for (int r = 0; r < 4; r++){
          const int grow = rbase + m * 16 + fq * 4 + r;
          float rs = 0.f;
          #pragma unroll
          for (int n = 0; n < 4; n++){
            const int gcol = cp * 128 + wn * 64 + n * 16 + fr;
            rs += (gcol < NP) ? __expf(acc[m][n][r] + obv[n]) : 0.f;
          }
          rs += __shfl_xor(rs, 1, 64);
          rs += __shfl_xor(rs, 2, 64);
          rs += __shfl_xor(rs, 4, 64);
          rs += __shfl_xor(rs, 8, 64);
          if (fr == 0 && grow < NN) atomicAdd(&rowsum[grow], rs);
        }
    } else {
      #pragma unroll
      for (int m = 0; m < 2; m++)
        #pragma unroll
        for (int r = 0; r < 4; r++){
          const int grow = rbase + m * 16 + fq * 4 + r;
          const bool rv = grow < NN;
          const float ri = rv ? 1.f / rowsum[grow] : 0.f;
          #pragma unroll
          for (int n = 0; n < 4; n++){
            const int gcol = cp * 128 + wn * 64 + n * 16 + fr;
            if (rv && gcol < NP)
              __builtin_nontemporal_store(ri * __expf(acc[m][n][r] + obv[n]),
                                          &out[(size_t)grow * NP + gcol]);
          }
        }
    }
  }
#undef STAGEA
}

// ---------------- host ----------------
extern "C" void kernel_launch(void* const* d_in, const int* in_sizes, int n_in,
                              void* d_out, int out_size, void* d_ws, size_t ws_size,
                              hipStream_t stream){
  const int*   user_ids = (const int*)d_in[0];
  const int*   prod_ids = (const int*)d_in[1];
  const int*   ei_u     = (const int*)d_in[2];
  const int*   ei_p     = (const int*)d_in[3];
  const float* utab     = (const float*)d_in[4];
  const float* ptab     = (const float*)d_in[5];
  const float* uW       = (const float*)d_in[6];
  const float* ub       = (const float*)d_in[7];
  const float* pW       = (const float*)d_in[8];
  const float* pb       = (const float*)d_in[9];
  const float* oW       = (const float*)d_in[10];
  const float* ob       = (const float*)d_in[11];
  float* out = (float*)d_out;
  (void)in_sizes; (void)n_in; (void)out_size; (void)ws_size;

  char* w = (char*)d_ws;
  size_t off = 0;
  auto alloc = [&](size_t bytes)->void*{
    void* p = w + off; off += (bytes + 255) & ~(size_t)255; return p;
  };
  int*   cnt    = (int*)alloc(2 * NN * 4);
  float* rowsum = (float*)alloc(NN * 4);
  float* dinv   = (float*)alloc(2 * NN * 4);     // [u | p]
  int*   ro     = (int*)alloc(2 * (NN + 1) * 4); // [u | p]
  int*   cur    = (int*)alloc(2 * NN * 4);
  int*   colb   = (int*)alloc((size_t)2 * NE * 4);
  unsigned short* xu_f  = (unsigned short*)alloc((size_t)NN * DD * 2);
  unsigned short* xp_f  = (unsigned short*)alloc((size_t)NN * DD * 2);
  unsigned short* xu2_f = (unsigned short*)alloc((size_t)NN * DD * 2);
  unsigned short* xp2_f = (unsigned short*)alloc((size_t)NN * DD * 2);
  unsigned short* comb_f= (unsigned short*)alloc((size_t)NRT_PAD * 8 * 64 * 8 * 2);
  unsigned short* hu    = (unsigned short*)alloc((size_t)NN * DD * 2);
  unsigned short* hp    = (unsigned short*)alloc((size_t)NN * DD * 2);
  unsigned short* WuF0 = (unsigned short*)alloc((size_t)DD * DD * 2);
  unsigned short* WuF1 = (unsigned short*)alloc((size_t)DD * DD * 2);
  unsigned short* WpF0 = (unsigned short*)alloc((size_t)DD * DD * 2);
  unsigned short* WpF1 = (unsigned short*)alloc((size_t)DD * DD * 2);
  unsigned short* WoF  = (unsigned short*)alloc((size_t)NCT_PAD * 8 * 64 * 8 * 2);

  hipMemsetAsync(cnt, 0, (2 * NN + NN) * 4, stream);             // cnt + rowsum
  hipMemsetAsync(comb_f + (size_t)NRT * 8 * 64 * 8, 0,
                 (size_t)(NRT_PAD - NRT) * 8 * 64 * 8 * 2, stream);  // pad rows only

  const int* src_u = ei_u;  const int* dst_u = ei_u + NE;
  const int* src_p = ei_p;  const int* dst_p = ei_p + NE;

  // mega-prologue: count + gathers + all weight packers
  k_prep<<<PREP_NWG, 256, 0, stream>>>(dst_u, dst_p, cnt,
                                       utab, user_ids, ptab, prod_ids, xu_f, xp_f,
                                       uW, pW, WuF0, WuF1, WpF0, WpF1, oW, WoF);
  k_scan2<<<2, 1024, 0, stream>>>(cnt, ro, cur, dinv);
  k_fill2<<<(2 * NE + 255) / 256, 256, 0, stream>>>(src_u, dst_u, src_p, dst_p, cur, colb);

  const int convGrid = (NRT + 3) / 4;   // 313
  dim3 aggBlk(16, 16);
  const int aggGrid = (NN + 15) / 16;

  // layer 1 (both towers per launch)
  k_conv2<<<dim3(convGrid, 2), 256, 0, stream>>>(xu_f, xp_f, WuF0, WpF0,
                                                 dinv, dinv + NN, hu, hp);
  k_agg2<<<dim3(aggGrid, 2), aggBlk, 0, stream>>>(hu, hp, dinv, dinv + NN, ro, colb,
                                                  ub, pb, xu2_f, xp2_f, 4, 0);
  // layer 2 -> comb fragments (user ktiles 0..3, product ktiles 4..7)
  k_conv2<<<dim3(convGrid, 2), 256, 0, stream>>>(xu2_f, xp2_f, WuF1, WpF1,
                                                 dinv, dinv + NN, hu, hp);
  k_agg2<<<dim3(aggGrid, 2), aggBlk, 0, stream>>>(hu, hp, dinv, dinv + NN, ro, colb,
                                                  ub + DD, pb + DD, comb_f, comb_f, 8, 4);

  // two-pass recompute softmax GEMM (B-stationary)
  k_big<0><<<NWG_BIG, 256, 0, stream>>>(comb_f, WoF, ob, rowsum, out);
  k_big<1><<<NWG_BIG, 256, 0, stream>>>(comb_f, WoF, ob, rowsum, out);
}